// Round 5
// baseline (410.045 us; speedup 1.0000x reference)
//
#include <hip/hip_runtime.h>
#include <cstddef>

#define TB 256

constexpr int Bb = 8, Ss = 4096, Dd = 1024, Kk = 64, Hh = 8;
constexpr float INV_TEMP = 10.0f;
constexpr float ATTN_SCALE = 0.08838834764831845f; // 1/sqrt(128)

typedef __attribute__((ext_vector_type(8))) short bf16x8;
typedef __attribute__((ext_vector_type(4))) float f32x4;

#define MFMA(a, b, c) __builtin_amdgcn_mfma_f32_16x16x32_bf16(a, b, c, 0, 0, 0)

// ---------------- workspace layout (bytes) ----------------
constexpr size_t SZ_W1  = (size_t)Kk*Dd*2;
constexpr size_t SZ_W2  = (size_t)Kk*Kk*2;
constexpr size_t SZ_WQ  = (size_t)3*Dd*Dd*2;
constexpr size_t SZ_WD  = (size_t)Dd*Dd*2;
constexpr size_t SZ_RW  = (size_t)Bb*Ss*Kk*2;
constexpr size_t SZ_AIF = (size_t)Bb*Kk*Dd*4;
constexpr size_t SZ_AI2 = (size_t)Bb*Kk*Dd*2;
constexpr size_t SZ_QK  = (size_t)Bb*Kk*2048*2;
constexpr size_t SZ_VT  = (size_t)Bb*Dd*Kk*2;
constexpr size_t SZ_AT  = (size_t)Bb*Kk*Dd*2;

constexpr size_t OFF_W1H = 0;
constexpr size_t OFF_W1L = OFF_W1H + SZ_W1;
constexpr size_t OFF_W2H = OFF_W1L + SZ_W1;
constexpr size_t OFF_W2L = OFF_W2H + SZ_W2;
constexpr size_t OFF_WQH = OFF_W2L + SZ_W2;
constexpr size_t OFF_WQL = OFF_WQH + SZ_WQ;
constexpr size_t OFF_WOH = OFF_WQL + SZ_WQ;
constexpr size_t OFF_WOL = OFF_WOH + SZ_WD;
constexpr size_t OFF_WPH = OFF_WOL + SZ_WD;
constexpr size_t OFF_WPL = OFF_WPH + SZ_WD;
constexpr size_t OFF_RWH = OFF_WPL + SZ_WD;
constexpr size_t OFF_RWL = OFF_RWH + SZ_RW;
constexpr size_t OFF_AIF = OFF_RWL + SZ_RW;
constexpr size_t OFF_AIH = OFF_AIF + SZ_AIF;
constexpr size_t OFF_AIL = OFF_AIH + SZ_AI2;
constexpr size_t OFF_U   = OFF_AIL + SZ_AI2;
// union phase 1: rwT split [b][64k][4096s]
constexpr size_t OFF_RTH = OFF_U;
constexpr size_t OFF_RTL = OFF_U + SZ_RW;
// union phase 2: anchor-space tensors
constexpr size_t OFF_QKH = OFF_U;
constexpr size_t OFF_QKL = OFF_QKH + SZ_QK;
constexpr size_t OFF_VTH = OFF_QKL + SZ_QK;
constexpr size_t OFF_VTL = OFF_VTH + SZ_VT;
constexpr size_t OFF_ATH = OFF_VTL + SZ_VT;
constexpr size_t OFF_ATL = OFF_ATH + SZ_AT;
constexpr size_t OFF_AOH = OFF_ATL + SZ_AT;
constexpr size_t OFF_AOL = OFF_AOH + SZ_AT;
constexpr size_t OFF_APH = OFF_AOL + SZ_AT;
constexpr size_t OFF_APL = OFF_APH + SZ_AT;

// ---------------- scalar helpers ----------------
__device__ inline ushort f2bf(float f) {
    union { float f; uint u; } v; v.f = f;
    return (ushort)((v.u + 0x7fffu + ((v.u >> 16) & 1u)) >> 16);
}
__device__ inline float bf2f(ushort h) {
    union { uint u; float f; } v; v.u = ((uint)h) << 16;
    return v.f;
}
__device__ inline void split2(float f, ushort& h, ushort& l) {
    h = f2bf(f);
    l = f2bf(f - bf2f(h));
}
__device__ inline f32x4 mm3(bf16x8 ah, bf16x8 al, bf16x8 bh, bf16x8 bl, f32x4 c) {
    c = MFMA(ah, bh, c);
    c = MFMA(ah, bl, c);
    c = MFMA(al, bh, c);
    return c;
}

// ---- swizzled LDS bf16 tile, logical [row][64] (stride 72 ushorts = 144B) ---
__device__ inline void st4(ushort* t, int row, int s0, ushort4 v) {
    char* p = (char*)t + row * 144 + ((((s0 >> 3) ^ ((row >> 2) & 7)) << 4) | ((s0 & 7) << 1));
    *(ushort4*)p = v;
}
__device__ inline void st1(ushort* t, int row, int s, ushort v) {
    char* p = (char*)t + row * 144 + ((((s >> 3) ^ ((row >> 2) & 7)) << 4) | ((s & 7) << 1));
    *(ushort*)p = v;
}
__device__ inline bf16x8 ldfrag(const ushort* t, int row, int sblk) {
    const char* p = (const char*)t + row * 144 + (((sblk ^ ((row >> 2) & 7))) << 4);
    return *(const bf16x8*)p;
}
__device__ inline void natf(ushort* thi, ushort* tlo, int row, int s0, float4 v) {
    ushort h0,h1,h2,h3,l0,l1,l2,l3;
    split2(v.x,h0,l0); split2(v.y,h1,l1); split2(v.z,h2,l2); split2(v.w,h3,l3);
    st4(thi, row, s0, make_ushort4(h0,h1,h2,h3));
    st4(tlo, row, s0, make_ushort4(l0,l1,l2,l3));
}
__device__ inline void trf(ushort* thi, ushort* tlo, int rowbase, int s0,
                           float4 a, float4 b, float4 c, float4 d) {
    float m[4][4] = {{a.x,b.x,c.x,d.x},{a.y,b.y,c.y,d.y},
                     {a.z,b.z,c.z,d.z},{a.w,b.w,c.w,d.w}};
#pragma unroll
    for (int i = 0; i < 4; ++i) {
        ushort h[4], l[4];
#pragma unroll
        for (int j = 0; j < 4; ++j) split2(m[i][j], h[j], l[j]);
        st4(thi, rowbase + i, s0, make_ushort4(h[0],h[1],h[2],h[3]));
        st4(tlo, rowbase + i, s0, make_ushort4(l[0],l[1],l[2],l[3]));
    }
}

__global__ __launch_bounds__(TB) void k_zero(float* __restrict__ p, int n4) {
    int i = blockIdx.x * TB + threadIdx.x;
    if (i < n4) ((float4*)p)[i] = make_float4(0.f, 0.f, 0.f, 0.f);
}

// ---------------------------------------------------------------------------
// k_prep: weight transpose+split -> bf16 hi/lo [out][in]
// ---------------------------------------------------------------------------
__global__ __launch_bounds__(TB) void k_prep(
    const float* __restrict__ w1, const float* __restrict__ w2,
    const float* __restrict__ wq, const float* __restrict__ wo,
    const float* __restrict__ wp,
    ushort* __restrict__ w1h, ushort* __restrict__ w1l,
    ushort* __restrict__ w2h, ushort* __restrict__ w2l,
    ushort* __restrict__ wqh, ushort* __restrict__ wql,
    ushort* __restrict__ woh, ushort* __restrict__ wol,
    ushort* __restrict__ wph, ushort* __restrict__ wpl)
{
    __shared__ float t[64][64];
    const int blk = blockIdx.x, tid = threadIdx.x;
    const float* in; ushort* oh; ushort* ol; int R, IC, r0, c0;
    if (blk < 16)        { in = w1; oh = w1h; ol = w1l; R = 1024; IC = 64;
                           r0 = blk * 64; c0 = 0; }
    else if (blk == 16)  { in = w2; oh = w2h; ol = w2l; R = 64;   IC = 64;
                           r0 = 0; c0 = 0; }
    else if (blk < 785)  { int i = blk - 17; in = wq; oh = wqh; ol = wql;
                           R = 1024; IC = 3072; r0 = (i / 48) * 64; c0 = (i % 48) * 64; }
    else if (blk < 1041) { int i = blk - 785; in = wo; oh = woh; ol = wol;
                           R = 1024; IC = 1024; r0 = (i / 16) * 64; c0 = (i % 16) * 64; }
    else                 { int i = blk - 1041; in = wp; oh = wph; ol = wpl;
                           R = 1024; IC = 1024; r0 = (i / 16) * 64; c0 = (i % 16) * 64; }
    {
        int r = tid >> 2, cq = (tid & 3) * 16;
        const float* ip = &in[(size_t)(r0 + r) * IC + c0 + cq];
#pragma unroll
        for (int q = 0; q < 4; ++q)
            *(float4*)&t[r][cq + q * 4] = *(const float4*)(ip + q * 4);
    }
    __syncthreads();
    {
        int oc = tid & 63, or0 = (tid >> 6) * 16;
        ushort th[16], tl[16];
#pragma unroll
        for (int i = 0; i < 16; ++i) split2(t[or0 + i][oc], th[i], tl[i]);
        size_t base = (size_t)(c0 + oc) * R + r0 + or0;
#pragma unroll
        for (int q = 0; q < 4; ++q) {
            *(ushort4*)&oh[base + q * 4] = make_ushort4(th[q*4], th[q*4+1], th[q*4+2], th[q*4+3]);
            *(ushort4*)&ol[base + q * 4] = make_ushort4(tl[q*4], tl[q*4+1], tl[q*4+2], tl[q*4+3]);
        }
    }
}

// ---------------------------------------------------------------------------
// k_route: fused routing, 512 threads (8 waves), register-prefetch dbuf.
// wave w: mtile = w&3 (16 tokens), nhalf = w>>2 (32 of 64 k-outputs).
// grid = 8b * 64 stiles(64 tok) = 512
// ---------------------------------------------------------------------------
__global__ __launch_bounds__(512) void k_route(
    const float* __restrict__ x, const float* __restrict__ efas,
    const float* __restrict__ w_e, const float* __restrict__ b_e,
    const float* __restrict__ b1, const float* __restrict__ b2,
    const ushort* __restrict__ w1h, const ushort* __restrict__ w1l,
    const ushort* __restrict__ w2h, const ushort* __restrict__ w2l,
    ushort* __restrict__ rwh, ushort* __restrict__ rwl,
    ushort* __restrict__ rth, ushort* __restrict__ rtl)
{
    __shared__ __align__(16) ushort xh[64*72], xl[64*72];
    __shared__ float smxm[8][16], smxs[8][16];
    const int tid = threadIdx.x, lane = tid & 63, wv = tid >> 6;
    const int r15 = lane & 15, gg = lane >> 4;
    const int mtile = wv & 3, nh = wv >> 2;
    const int b = blockIdx.x & 7, t0 = (blockIdx.x >> 3) * 64;

    // staging assignment: 512 threads cover 64 rows x 64 cols fp32 (8 f/thread)
    const int srow = tid >> 3, scol = (tid & 7) * 8;
    const float* xbase = &x[((size_t)b*Ss + t0 + srow)*Dd + scol];

    float4 pa, pb;
    pa = *(const float4*)(xbase);
    pb = *(const float4*)(xbase + 4);

    f32x4 acc[2];
#pragma unroll
    for (int n = 0; n < 2; ++n) acc[n] = (f32x4)0.f;

    for (int kc = 0; kc < 16; ++kc) {
        natf(xh, xl, srow, scol, pa);
        natf(xh, xl, srow, scol + 4, pb);
        __syncthreads();
        if (kc < 15) {
            pa = *(const float4*)(xbase + (kc + 1) * 64);
            pb = *(const float4*)(xbase + (kc + 1) * 64 + 4);
        }
#pragma unroll
        for (int ks = 0; ks < 2; ++ks) {
            bf16x8 ah = ldfrag(xh, mtile*16 + r15, ks*4 + gg);
            bf16x8 al = ldfrag(xl, mtile*16 + r15, ks*4 + gg);
#pragma unroll
            for (int n = 0; n < 2; ++n) {
                int nt = nh*2 + n;
                size_t wi = (size_t)(nt*16 + r15)*Dd + kc*64 + ks*32 + gg*8;
                acc[n] = mm3(ah, al, *(const bf16x8*)&w1h[wi],
                             *(const bf16x8*)&w1l[wi], acc[n]);
            }
        }
        __syncthreads();
    }
    // h = relu(acc+b1) -> xh/xl; wave writes rows mtile*16+gg*4+j, cols nh*32+n*16+r15
#pragma unroll
    for (int n = 0; n < 2; ++n) {
        int nt = nh*2 + n;
        float b1v = b1[nt*16 + r15];
#pragma unroll
        for (int j = 0; j < 4; ++j) {
            float hv = fmaxf(acc[n][j] + b1v, 0.f);
            ushort hh, hl; split2(hv, hh, hl);
            st1(xh, mtile*16 + gg*4 + j, nt*16 + r15, hh);
            st1(xl, mtile*16 + gg*4 + j, nt*16 + r15, hl);
        }
    }
    __syncthreads();
    // h @ w2
    f32x4 a2[2];
#pragma unroll
    for (int n = 0; n < 2; ++n) a2[n] = (f32x4)0.f;
#pragma unroll
    for (int ks = 0; ks < 2; ++ks) {
        bf16x8 ah = ldfrag(xh, mtile*16 + r15, ks*4 + gg);
        bf16x8 al = ldfrag(xl, mtile*16 + r15, ks*4 + gg);
#pragma unroll
        for (int n = 0; n < 2; ++n) {
            int nt = nh*2 + n;
            size_t wi = (size_t)(nt*16 + r15)*Kk + ks*32 + gg*8;
            a2[n] = mm3(ah, al, *(const bf16x8*)&w2h[wi],
                        *(const bf16x8*)&w2l[wi], a2[n]);
        }
    }
    // logits + cross-wave softmax
    float wev[2], bev[2], b2v[2];
#pragma unroll
    for (int n = 0; n < 2; ++n) {
        int nt = nh*2 + n;
        wev[n] = w_e[nt*16 + r15]; bev[n] = b_e[nt*16 + r15]; b2v[n] = b2[nt*16 + r15];
    }
    float tt[4][2], mloc[4], sloc[4];
#pragma unroll
    for (int j = 0; j < 4; ++j) {
        int row = t0 + mtile*16 + gg*4 + j;
        float ef = efas[(size_t)b*Ss + row];
#pragma unroll
        for (int n = 0; n < 2; ++n)
            tt[j][n] = (a2[n][j] + b2v[n] + 2.f*(ef*wev[n] + bev[n])) * INV_TEMP;
        float m = fmaxf(tt[j][0], tt[j][1]);
#pragma unroll
        for (int off = 1; off <= 8; off <<= 1) m = fmaxf(m, __shfl_xor(m, off));
        float s = __expf(tt[j][0] - m) + __expf(tt[j][1] - m);
#pragma unroll
        for (int off = 1; off <= 8; off <<= 1) s += __shfl_xor(s, off);
        mloc[j] = m; sloc[j] = s;
    }
    if (r15 == 0) {
#pragma unroll
        for (int j = 0; j < 4; ++j) {
            smxm[wv][gg*4 + j] = mloc[j];
            smxs[wv][gg*4 + j] = sloc[j];
        }
    }
    __syncthreads();
    float pr[4][2];
#pragma unroll
    for (int j = 0; j < 4; ++j) {
        float mp = smxm[wv ^ 4][gg*4 + j], sp = smxs[wv ^ 4][gg*4 + j];
        float M = fmaxf(mloc[j], mp);
        float S = sloc[j]*__expf(mloc[j] - M) + sp*__expf(mp - M);
        float inv = 1.f / S;
#pragma unroll
        for (int n = 0; n < 2; ++n) pr[j][n] = __expf(tt[j][n] - M) * inv;
    }
    // natural split write
#pragma unroll
    for (int j = 0; j < 4; ++j) {
        int row = t0 + mtile*16 + gg*4 + j;
#pragma unroll
        for (int n = 0; n < 2; ++n) {
            int nt = nh*2 + n;
            ushort hh, hl; split2(pr[j][n], hh, hl);
            size_t o = ((size_t)b*Ss + row)*Kk + nt*16 + r15;
            rwh[o] = hh; rwl[o] = hl;
        }
    }
    // transposed split write rwT[b][k][s]
#pragma unroll
    for (int n = 0; n < 2; ++n) {
        int nt = nh*2 + n;
        ushort h0,h1,h2,h3,l0,l1,l2,l3;
        split2(pr[0][n],h0,l0); split2(pr[1][n],h1,l1);
        split2(pr[2][n],h2,l2); split2(pr[3][n],h3,l3);
        size_t o = ((size_t)b*Kk + nt*16 + r15)*Ss + t0 + mtile*16 + gg*4;
        *(ushort4*)&rth[o] = make_ushort4(h0,h1,h2,h3);
        *(ushort4*)&rtl[o] = make_ushort4(l0,l1,l2,l3);
    }
}

// ---------------------------------------------------------------------------
// k_anchor: ai[b,k,d] += sum_s rw[s,k]*x[s,d]; A=rwT reg-direct, B=xT via LDS
// with register prefetch. grid = 8b * 16dt(64 d) * 8sc(512 s) = 1024
// ---------------------------------------------------------------------------
__global__ __launch_bounds__(TB) void k_anchor(
    const float* __restrict__ x, const ushort* __restrict__ rth,
    const ushort* __restrict__ rtl, float* __restrict__ ai)
{
    __shared__ __align__(16) ushort bh_t[64*72], bl_t[64*72]; // xT [64 d][64 s]
    const int tid = threadIdx.x, lane = tid & 63, wv = tid >> 6;
    const int r15 = lane & 15, gg = lane >> 4;
    const int b = blockIdx.x & 7, dt = (blockIdx.x >> 3) & 15, sc = blockIdx.x >> 7;

    const int d0 = (tid & 15) * 4, s0q = (tid >> 4) * 4;
    const float* xb0 = &x[((size_t)b*Ss + sc*512 + s0q)*Dd + dt*64 + d0];

    float4 r0, r1, r2, r3;
    r0 = *(const float4*)(xb0);
    r1 = *(const float4*)(xb0 + Dd);
    r2 = *(const float4*)(xb0 + 2*Dd);
    r3 = *(const float4*)(xb0 + 3*Dd);

    f32x4 acc[4];
#pragma unroll
    for (int mt = 0; mt < 4; ++mt) acc[mt] = (f32x4)0.f;

    for (int cc = 0; cc < 8; ++cc) {
        trf(bh_t, bl_t, d0, s0q, r0, r1, r2, r3);
        __syncthreads();
        if (cc < 7) {
            const float* nb = xb0 + (size_t)(cc + 1) * 64 * Dd;
            r0 = *(const float4*)(nb);
            r1 = *(const float4*)(nb + Dd);
            r2 = *(const float4*)(nb + 2*Dd);
            r3 = *(const float4*)(nb + 3*Dd);
        }
        const int sb = sc*512 + cc*64;
#pragma unroll
        for (int ks = 0; ks < 2; ++ks) {
            bf16x8 xbh = ldfrag(bh_t, wv*16 + r15, ks*4 + gg);
            bf16x8 xbl = ldfrag(bl_t, wv*16 + r15, ks*4 + gg);
#pragma unroll
            for (int mt = 0; mt < 4; ++mt) {
                size_t ri = ((size_t)b*Kk + mt*16 + r15)*Ss + sb + ks*32 + gg*8;
                bf16x8 ah = *(const bf16x8*)&rth[ri];
                bf16x8 al = *(const bf16x8*)&rtl[ri];
                acc[mt] = mm3(ah, al, xbh, xbl, acc[mt]);
            }
        }
        __syncthreads();
    }
#pragma unroll
    for (int mt = 0; mt < 4; ++mt)
#pragma unroll
      for (int j = 0; j < 4; ++j) {
        int k = mt*16 + gg*4 + j;
        int d = dt*64 + wv*16 + r15;
        atomicAdd(&ai[((size_t)b*Kk + k)*Dd + d], acc[mt][j]);
      }
}

// ---------------------------------------------------------------------------
// k_cvt: ai fp32 -> split bf16 natural
// ---------------------------------------------------------------------------
__global__ __launch_bounds__(TB) void k_cvt(
    const float* __restrict__ ai, ushort* __restrict__ aih, ushort* __restrict__ ail)
{
    size_t i = ((size_t)blockIdx.x * TB + threadIdx.x) * 4;
    float4 v = *(const float4*)&ai[i];
    ushort h0,h1,h2,h3,l0,l1,l2,l3;
    split2(v.x,h0,l0); split2(v.y,h1,l1); split2(v.z,h2,l2); split2(v.w,h3,l3);
    *(ushort4*)&aih[i] = make_ushort4(h0,h1,h2,h3);
    *(ushort4*)&ail[i] = make_ushort4(l0,l1,l2,l3);
}

// ---------------------------------------------------------------------------
// k_gemm: C[b,64,NDIM] = A-split[b,64,1024] @ WT-split (+bias); reg-direct,
// n-tile 64 (1 ntile per wave). grid = 8 * NDIM/64
// EPI 0: natural-split out (stride 1024). EPI 1 (qkv): n<2048 natural stride
// 2048; n>=2048 transposed -> VT. EPI 2: transposed out, no bias.
// ---------------------------------------------------------------------------
template <int NDIM, int EPI>
__global__ __launch_bounds__(TB) void k_gemm(
    const ushort* __restrict__ AH, const ushort* __restrict__ AL,
    const ushort* __restrict__ WH, const ushort* __restrict__ WL,
    const float* __restrict__ bias,
    ushort* __restrict__ OH, ushort* __restrict__ OL,
    ushort* __restrict__ TH, ushort* __restrict__ TL)
{
    const int tid = threadIdx.x, lane = tid & 63, wv = tid >> 6;
    const int r15 = lane & 15, gg = lane >> 4;
    constexpr int NT = NDIM / 64;
    const int b = blockIdx.x / NT, n0 = (blockIdx.x % NT) * 64;

    f32x4 acc[4];
#pragma unroll
    for (int mt = 0; mt < 4; ++mt) acc[mt] = (f32x4)0.f;

    for (int kc = 0; kc < 32; ++kc) {
        const int kb = kc * 32 + gg * 8;
        size_t widx = ((size_t)(n0 + wv*16 + r15))*Dd + kb;
        bf16x8 bh = *(const bf16x8*)&WH[widx];
        bf16x8 bl = *(const bf16x8*)&WL[widx];
#pragma unroll
        for (int mt = 0; mt < 4; ++mt) {
            size_t aidx = ((size_t)b*64 + mt*16 + r15)*Dd + kb;
            acc[mt] = mm3(*(const bf16x8*)&AH[aidx], *(const bf16x8*)&AL[aidx],
                          bh, bl, acc[mt]);
        }
    }
    const int n = n0 + wv*16 + r15;
    float bb = (EPI == 2) ? 0.f : bias[n];
#pragma unroll
    for (int mt = 0; mt < 4; ++mt) {
        if (EPI == 2 || (EPI == 1 && n0 >= 2048)) {
            ushort h[4], l[4];
#pragma unroll
            for (int j = 0; j < 4; ++j) split2(acc[mt][j] + bb, h[j], l[j]);
            int nn = (EPI == 1) ? n - 2048 : n;
            size_t o = ((size_t)b*Dd + nn)*64 + mt*16 + gg*4;
            *(ushort4*)&TH[o] = make_ushort4(h[0],h[1],h[2],h[3]);
            *(ushort4*)&TL[o] = make_ushort4(l[0],l[1],l[2],l[3]);
        } else {
            constexpr int OST = (EPI == 1) ? 2048 : 1024;
#pragma unroll
            for (int j = 0; j < 4; ++j) {
                ushort hh, hl; split2(acc[mt][j] + bb, hh, hl);
                size_t o = ((size_t)b*64 + mt*16 + gg*4 + j)*OST + n;
                OH[o] = hh; OL[o] = hl;
            }
        }
    }
}

// ---------------------------------------------------------------------------
// k_attn: per (b,h): scores (reg-direct Q,K), softmax, PV (reg-direct VT)
// grid = 64
// ---------------------------------------------------------------------------
__global__ __launch_bounds__(TB) void k_attn(
    const ushort* __restrict__ qkh, const ushort* __restrict__ qkl,
    const ushort* __restrict__ vth, const ushort* __restrict__ vtl,
    ushort* __restrict__ atth, ushort* __restrict__ attl)
{
    __shared__ __align__(16) ushort ph[64*72], pl[64*72];
    const int tid = threadIdx.x, lane = tid & 63, wv = tid >> 6;
    const int r15 = lane & 15, gg = lane >> 4;
    const int b = blockIdx.x >> 3, h = blockIdx.x & 7;

    f32x4 sc[4];
#pragma unroll
    for (int nt = 0; nt < 4; ++nt) sc[nt] = (f32x4)0.f;
#pragma unroll
    for (int kb = 0; kb < 4; ++kb) {
        size_t qi = ((size_t)b*64 + wv*16 + r15)*2048 + h*128 + kb*32 + gg*8;
        bf16x8 ah = *(const bf16x8*)&qkh[qi];
        bf16x8 al = *(const bf16x8*)&qkl[qi];
#pragma unroll
        for (int nt = 0; nt < 4; ++nt) {
            size_t ki = ((size_t)b*64 + nt*16 + r15)*2048 + 1024 + h*128 + kb*32 + gg*8;
            sc[nt] = mm3(ah, al, *(const bf16x8*)&qkh[ki],
                         *(const bf16x8*)&qkl[ki], sc[nt]);
        }
    }
    float pr[4][4];
#pragma unroll
    for (int j = 0; j < 4; ++j) {
        float t[4];
#pragma unroll
        for (int nt = 0; nt < 4; ++nt) t[nt] = sc[nt][j] * ATTN_SCALE;
        float m = fmaxf(fmaxf(t[0],t[1]), fmaxf(t[2],t[3]));
#pragma unroll
        for (int off = 1; off <= 8; off <<= 1) m = fmaxf(m, __shfl_xor(m, off));
        float s = 0.f;
#pragma unroll
        for (int nt = 0; nt < 4; ++nt) { t[nt] = __expf(t[nt] - m); s += t[nt]; }
#pragma unroll
        for (int off = 1; off <= 8; off <<= 1) s += __shfl_xor(s, off);
        float inv = 1.f / s;
#pragma unroll
        for (int nt = 0; nt < 4; ++nt) pr[j][nt] = t[nt] * inv;
    }
#pragma unroll
    for (int j = 0; j < 4; ++j)
#pragma unroll
      for (int nt = 0; nt < 4; ++nt) {
        ushort hh, hl; split2(pr[j][nt], hh, hl);
        st1(ph, wv*16 + gg*4 + j, nt*16 + r15, hh);
        st1(pl, wv*16 + gg*4 + j, nt*16 + r15, hl);
      }
    __syncthreads();
    f32x4 o[8];
#pragma unroll
    for (int nt = 0; nt < 8; ++nt) o[nt] = (f32x4)0.f;
#pragma unroll
    for (int ks = 0; ks < 2; ++ks) {
        bf16x8 ah = ldfrag(ph, wv*16 + r15, ks*4 + gg);
        bf16x8 al = ldfrag(pl, wv*16 + r15, ks*4 + gg);
#pragma unroll
        for (int nt = 0; nt < 8; ++nt) {
            size_t vi = ((size_t)b*Dd + h*128 + nt*16 + r15)*64 + ks*32 + gg*8;
            o[nt] = mm3(ah, al, *(const bf16x8*)&vth[vi],
                        *(const bf16x8*)&vtl[vi], o[nt]);
        }
    }
#pragma unroll
    for (int nt = 0; nt < 8; ++nt)
#pragma unroll
      for (int j = 0; j < 4; ++j) {
        ushort hh, hl; split2(o[nt][j], hh, hl);
        size_t oo = ((size_t)b*64 + wv*16 + gg*4 + j)*Dd + h*128 + nt*16 + r15;
        atth[oo] = hh; attl[oo] = hl;
      }
}

// ---------------------------------------------------------------------------
// k_scatter: out = rw @ aop + b_p  (reg-direct both sides, LDS-free)
// grid = 8b * 32st(128 tok) * 8dt(128 d) = 2048
// ---------------------------------------------------------------------------
__global__ __launch_bounds__(TB) void k_scatter(
    const ushort* __restrict__ rwh, const ushort* __restrict__ rwl,
    const ushort* __restrict__ aph, const ushort* __restrict__ apl,
    const float* __restrict__ b_p, float* __restrict__ out)
{
    const int tid = threadIdx.x, lane = tid & 63, wv = tid >> 6;
    const int r15 = lane & 15, gg = lane >> 4;
    const int b = blockIdx.x & 7, st = (blockIdx.x >> 3) & 31, dt = blockIdx.x >> 8;
    const int t0 = st * 128;

    f32x4 acc[2][8];
#pragma unroll
    for (int mt = 0; mt < 2; ++mt)
#pragma unroll
      for (int nt = 0; nt < 8; ++nt) acc[mt][nt] = (f32x4)0.f;

#pragma unroll
    for (int ks = 0; ks < 2; ++ks) {
        bf16x8 ah[2], al[2];
#pragma unroll
        for (int mt = 0; mt < 2; ++mt) {
            size_t ri = ((size_t)b*Ss + t0 + wv*32 + mt*16 + r15)*Kk + ks*32 + gg*8;
            ah[mt] = *(const bf16x8*)&rwh[ri];
            al[mt] = *(const bf16x8*)&rwl[ri];
        }
#pragma unroll
        for (int nt = 0; nt < 8; ++nt) {
            size_t bi = ((size_t)b*Dd + dt*128 + nt*16 + r15)*Kk + ks*32 + gg*8;
            bf16x8 bh = *(const bf16x8*)&aph[bi];
            bf16x8 bl = *(const bf16x8*)&apl[bi];
#pragma unroll
            for (int mt = 0; mt < 2; ++mt)
                acc[mt][nt] = mm3(ah[mt], al[mt], bh, bl, acc[mt][nt]);
        }
    }
#pragma unroll
    for (int nt = 0; nt < 8; ++nt) {
        float bp = b_p[dt*128 + nt*16 + r15];
#pragma unroll
        for (int mt = 0; mt < 2; ++mt)
#pragma unroll
          for (int j = 0; j < 4; ++j)
            out[((size_t)b*Ss + t0 + wv*32 + mt*16 + gg*4 + j)*Dd + dt*128 + nt*16 + r15]
                = acc[mt][nt][j] + bp;
    }
}

extern "C" void kernel_launch(void* const* d_in, const int* in_sizes, int n_in,
                              void* d_out, int out_size, void* d_ws, size_t ws_size,
                              hipStream_t stream)
{
    const float* x     = (const float*)d_in[0];
    const float* efas  = (const float*)d_in[1];
    const float* w_e   = (const float*)d_in[2];
    const float* b_e   = (const float*)d_in[3];
    const float* w1    = (const float*)d_in[4];
    const float* b1    = (const float*)d_in[5];
    const float* w2    = (const float*)d_in[6];
    const float* b2    = (const float*)d_in[7];
    const float* w_qkv = (const float*)d_in[8];
    const float* b_qkv = (const float*)d_in[9];
    const float* w_o   = (const float*)d_in[10];
    const float* b_o   = (const float*)d_in[11];
    const float* w_p   = (const float*)d_in[12];
    const float* b_p   = (const float*)d_in[13];
    float* out = (float*)d_out;
    char* ws = (char*)d_ws;

    ushort* w1h = (ushort*)(ws + OFF_W1H); ushort* w1l = (ushort*)(ws + OFF_W1L);
    ushort* w2h = (ushort*)(ws + OFF_W2H); ushort* w2l = (ushort*)(ws + OFF_W2L);
    ushort* wqh = (ushort*)(ws + OFF_WQH); ushort* wql = (ushort*)(ws + OFF_WQL);
    ushort* woh = (ushort*)(ws + OFF_WOH); ushort* wol = (ushort*)(ws + OFF_WOL);
    ushort* wph = (ushort*)(ws + OFF_WPH); ushort* wpl = (ushort*)(ws + OFF_WPL);
    ushort* rwh = (ushort*)(ws + OFF_RWH); ushort* rwl = (ushort*)(ws + OFF_RWL);
    float*  aif = (float*) (ws + OFF_AIF);
    ushort* aih = (ushort*)(ws + OFF_AIH); ushort* ail = (ushort*)(ws + OFF_AIL);
    ushort* rth = (ushort*)(ws + OFF_RTH); ushort* rtl = (ushort*)(ws + OFF_RTL);
    ushort* qkh = (ushort*)(ws + OFF_QKH); ushort* qkl = (ushort*)(ws + OFF_QKL);
    ushort* vth = (ushort*)(ws + OFF_VTH); ushort* vtl = (ushort*)(ws + OFF_VTL);
    ushort* ath = (ushort*)(ws + OFF_ATH); ushort* atl = (ushort*)(ws + OFF_ATL);
    ushort* aoh = (ushort*)(ws + OFF_AOH); ushort* aol = (ushort*)(ws + OFF_AOL);
    ushort* aph = (ushort*)(ws + OFF_APH); ushort* apl = (ushort*)(ws + OFF_APL);

    hipLaunchKernelGGL(k_prep, dim3(1297), dim3(TB), 0, stream,
                       w1, w2, w_qkv, w_o, w_p,
                       w1h, w1l, w2h, w2l, wqh, wql, woh, wol, wph, wpl);
    hipLaunchKernelGGL(k_zero, dim3(512), dim3(TB), 0, stream,
                       aif, (int)(SZ_AIF / 16));
    hipLaunchKernelGGL(k_route, dim3(512), dim3(512), 0, stream,
                       x, efas, w_e, b_e, b1, b2, w1h, w1l, w2h, w2l,
                       rwh, rwl, rth, rtl);
    hipLaunchKernelGGL(k_anchor, dim3(1024), dim3(TB), 0, stream, x, rth, rtl, aif);
    hipLaunchKernelGGL(k_cvt, dim3(512), dim3(TB), 0, stream, aif, aih, ail);
    hipLaunchKernelGGL((k_gemm<3072, 1>), dim3(384), dim3(TB), 0, stream,
                       aih, ail, wqh, wql, b_qkv, qkh, qkl, vth, vtl);
    hipLaunchKernelGGL(k_attn, dim3(64), dim3(TB), 0, stream,
                       qkh, qkl, vth, vtl, ath, atl);
    hipLaunchKernelGGL((k_gemm<1024, 0>), dim3(128), dim3(TB), 0, stream,
                       ath, atl, woh, wol, b_o, aoh, aol,
                       (ushort*)nullptr, (ushort*)nullptr);
    hipLaunchKernelGGL((k_gemm<1024, 2>), dim3(128), dim3(TB), 0, stream,
                       aoh, aol, wph, wpl, (const float*)nullptr,
                       (ushort*)nullptr, (ushort*)nullptr, aph, apl);
    hipLaunchKernelGGL(k_scatter, dim3(2048), dim3(TB), 0, stream,
                       rwh, rwl, aph, apl, b_p, out);
}

// Round 6
// 396.070 us; speedup vs baseline: 1.0353x; 1.0353x over previous
//
#include <hip/hip_runtime.h>
#include <cstddef>

#define TB 256

constexpr int Bb = 8, Ss = 4096, Dd = 1024, Kk = 64, Hh = 8;
constexpr float INV_TEMP = 10.0f;
constexpr float ATTN_SCALE = 0.08838834764831845f; // 1/sqrt(128)

typedef __attribute__((ext_vector_type(8))) short bf16x8;
typedef __attribute__((ext_vector_type(4))) float f32x4;

#define MFMA(a, b, c) __builtin_amdgcn_mfma_f32_16x16x32_bf16(a, b, c, 0, 0, 0)

// ---------------- workspace layout (bytes) ----------------
constexpr size_t SZ_W1  = (size_t)Kk*Dd*2;        // w1F fragment-packed
constexpr size_t SZ_W2  = (size_t)Kk*Kk*2;        // w2F fragment-packed
constexpr size_t SZ_WQ  = (size_t)3*Dd*Dd*2;
constexpr size_t SZ_WD  = (size_t)Dd*Dd*2;
constexpr size_t SZ_RW  = (size_t)Bb*Ss*Kk*2;
constexpr size_t SZ_AIF = (size_t)Bb*Kk*Dd*4;
constexpr size_t SZ_AI2 = (size_t)Bb*Kk*Dd*2;
constexpr size_t SZ_QK  = (size_t)Bb*Kk*2048*2;
constexpr size_t SZ_VT  = (size_t)Bb*Dd*Kk*2;
constexpr size_t SZ_AT  = (size_t)Bb*Kk*Dd*2;

constexpr size_t OFF_W1H = 0;
constexpr size_t OFF_W1L = OFF_W1H + SZ_W1;
constexpr size_t OFF_W2H = OFF_W1L + SZ_W1;
constexpr size_t OFF_W2L = OFF_W2H + SZ_W2;
constexpr size_t OFF_WQH = OFF_W2L + SZ_W2;
constexpr size_t OFF_WQL = OFF_WQH + SZ_WQ;
constexpr size_t OFF_WOH = OFF_WQL + SZ_WQ;
constexpr size_t OFF_WOL = OFF_WOH + SZ_WD;
constexpr size_t OFF_WPH = OFF_WOL + SZ_WD;
constexpr size_t OFF_WPL = OFF_WPH + SZ_WD;
constexpr size_t OFF_RWH = OFF_WPL + SZ_WD;       // rw natural split [b][s][64]
constexpr size_t OFF_RWL = OFF_RWH + SZ_RW;
constexpr size_t OFF_AIF = OFF_RWL + SZ_RW;
constexpr size_t OFF_AIH = OFF_AIF + SZ_AIF;
constexpr size_t OFF_AIL = OFF_AIH + SZ_AI2;
constexpr size_t OFF_U   = OFF_AIL + SZ_AI2;
// union phase 1: rwF fragment-packed [b][stile64][kt4][ks2][512u]
constexpr size_t OFF_RFH = OFF_U;
constexpr size_t OFF_RFL = OFF_U + SZ_RW;
// union phase 2: anchor-space tensors
constexpr size_t OFF_QKH = OFF_U;
constexpr size_t OFF_QKL = OFF_QKH + SZ_QK;
constexpr size_t OFF_VTH = OFF_QKL + SZ_QK;
constexpr size_t OFF_VTL = OFF_VTH + SZ_VT;
constexpr size_t OFF_ATH = OFF_VTL + SZ_VT;
constexpr size_t OFF_ATL = OFF_ATH + SZ_AT;
constexpr size_t OFF_AOH = OFF_ATL + SZ_AT;
constexpr size_t OFF_AOL = OFF_AOH + SZ_AT;
constexpr size_t OFF_APH = OFF_AOL + SZ_AT;
constexpr size_t OFF_APL = OFF_APH + SZ_AT;

// ---------------- scalar helpers ----------------
__device__ inline ushort f2bf(float f) {
    union { float f; uint u; } v; v.f = f;
    return (ushort)((v.u + 0x7fffu + ((v.u >> 16) & 1u)) >> 16);
}
__device__ inline float bf2f(ushort h) {
    union { uint u; float f; } v; v.u = ((uint)h) << 16;
    return v.f;
}
__device__ inline void split2(float f, ushort& h, ushort& l) {
    h = f2bf(f);
    l = f2bf(f - bf2f(h));
}
__device__ inline void cvt8(float4 a, float4 b, bf16x8& h8, bf16x8& l8) {
    float f[8] = {a.x, a.y, a.z, a.w, b.x, b.y, b.z, b.w};
#pragma unroll
    for (int i = 0; i < 8; ++i) {
        ushort hh, ll; split2(f[i], hh, ll);
        h8[i] = (short)hh; l8[i] = (short)ll;
    }
}
__device__ inline f32x4 mm3(bf16x8 ah, bf16x8 al, bf16x8 bh, bf16x8 bl, f32x4 c) {
    c = MFMA(ah, bh, c);
    c = MFMA(ah, bl, c);
    c = MFMA(al, bh, c);
    return c;
}

// lgkm-only barrier: LDS visibility without draining vmem (keeps loads in flight)
__device__ inline void lds_barrier() {
    __builtin_amdgcn_sched_barrier(0);
    asm volatile("s_waitcnt lgkmcnt(0)" ::: "memory");
    __builtin_amdgcn_s_barrier();
    __builtin_amdgcn_sched_barrier(0);
}

// ---- swizzled LDS bf16 tile, logical [row][64] (stride 72 ushorts = 144B) ---
__device__ inline void st4(ushort* t, int row, int s0, ushort4 v) {
    char* p = (char*)t + row * 144 + ((((s0 >> 3) ^ ((row >> 2) & 7)) << 4) | ((s0 & 7) << 1));
    *(ushort4*)p = v;
}
__device__ inline void st1(ushort* t, int row, int s, ushort v) {
    char* p = (char*)t + row * 144 + ((((s >> 3) ^ ((row >> 2) & 7)) << 4) | ((s & 7) << 1));
    *(ushort*)p = v;
}
__device__ inline bf16x8 ldfrag(const ushort* t, int row, int sblk) {
    const char* p = (const char*)t + row * 144 + (((sblk ^ ((row >> 2) & 7))) << 4);
    return *(const bf16x8*)p;
}
__device__ inline void trf(ushort* thi, ushort* tlo, int rowbase, int s0,
                           float4 a, float4 b, float4 c, float4 d) {
    float m[4][4] = {{a.x,b.x,c.x,d.x},{a.y,b.y,c.y,d.y},
                     {a.z,b.z,c.z,d.z},{a.w,b.w,c.w,d.w}};
#pragma unroll
    for (int i = 0; i < 4; ++i) {
        ushort h[4], l[4];
#pragma unroll
        for (int j = 0; j < 4; ++j) split2(m[i][j], h[j], l[j]);
        st4(thi, rowbase + i, s0, make_ushort4(h[0],h[1],h[2],h[3]));
        st4(tlo, rowbase + i, s0, make_ushort4(l[0],l[1],l[2],l[3]));
    }
}

__global__ __launch_bounds__(TB) void k_zero(float* __restrict__ p, int n4) {
    int i = blockIdx.x * TB + threadIdx.x;
    if (i < n4) ((float4*)p)[i] = make_float4(0.f, 0.f, 0.f, 0.f);
}

// ---------------------------------------------------------------------------
// k_prep: w1/w2 -> fragment-major split blocks; wq/wo/wp -> [out][in] split
// fragment block (ntile,kc,ks): 512 ushorts, addr (gg*16+r15)*8+elem
// ---------------------------------------------------------------------------
__global__ __launch_bounds__(TB) void k_prep(
    const float* __restrict__ w1, const float* __restrict__ w2,
    const float* __restrict__ wq, const float* __restrict__ wo,
    const float* __restrict__ wp,
    ushort* __restrict__ w1h, ushort* __restrict__ w1l,
    ushort* __restrict__ w2h, ushort* __restrict__ w2l,
    ushort* __restrict__ wqh, ushort* __restrict__ wql,
    ushort* __restrict__ woh, ushort* __restrict__ wol,
    ushort* __restrict__ wph, ushort* __restrict__ wpl)
{
    __shared__ float t[64][64];
    const int blk = blockIdx.x, tid = threadIdx.x;
    const float* in; ushort* oh; ushort* ol; int R, IC, r0, c0, mode;
    if (blk < 16)        { in = w1; oh = w1h; ol = w1l; R = 1024; IC = 64;
                           r0 = blk * 64; c0 = 0; mode = 1; }
    else if (blk == 16)  { in = w2; oh = w2h; ol = w2l; R = 64;   IC = 64;
                           r0 = 0; c0 = 0; mode = 2; }
    else if (blk < 785)  { int i = blk - 17; in = wq; oh = wqh; ol = wql;
                           R = 1024; IC = 3072; r0 = (i / 48) * 64; c0 = (i % 48) * 64; mode = 0; }
    else if (blk < 1041) { int i = blk - 785; in = wo; oh = woh; ol = wol;
                           R = 1024; IC = 1024; r0 = (i / 16) * 64; c0 = (i % 16) * 64; mode = 0; }
    else                 { int i = blk - 1041; in = wp; oh = wph; ol = wpl;
                           R = 1024; IC = 1024; r0 = (i / 16) * 64; c0 = (i % 16) * 64; mode = 0; }
    {
        int r = tid >> 2, cq = (tid & 3) * 16;
        const float* ip = &in[(size_t)(r0 + r) * IC + c0 + cq];
#pragma unroll
        for (int q = 0; q < 4; ++q)
            *(float4*)&t[r][cq + q * 4] = *(const float4*)(ip + q * 4);
    }
    __syncthreads();
    {
        int oc = tid & 63, or0 = (tid >> 6) * 16;
        ushort th[16], tl[16];
#pragma unroll
        for (int i = 0; i < 16; ++i) split2(t[or0 + i][oc], th[i], tl[i]);
        if (mode == 0) {
            size_t base = (size_t)(c0 + oc) * R + r0 + or0;
#pragma unroll
            for (int q = 0; q < 4; ++q) {
                *(ushort4*)&oh[base + q*4] = make_ushort4(th[q*4], th[q*4+1], th[q*4+2], th[q*4+3]);
                *(ushort4*)&ol[base + q*4] = make_ushort4(tl[q*4], tl[q*4+1], tl[q*4+2], tl[q*4+3]);
            }
        } else {
            int nt = oc >> 4, r15o = oc & 15;
#pragma unroll
            for (int ii = 0; ii < 16; ++ii) {
                int i = or0 + ii;
                int ks = i >> 5, gga = (i >> 3) & 3, el = i & 7;
                size_t idx = (mode == 1)
                    ? (((size_t)(nt*16 + blk)*2 + ks)*512 + (gga*16 + r15o)*8 + el)
                    : (((size_t)nt*2 + ks)*512 + (gga*16 + r15o)*8 + el);
                oh[idx] = th[ii]; ol[idx] = tl[ii];
            }
        }
    }
}

// ---------------------------------------------------------------------------
// k_route: barrier-free. Each wave owns 16 tokens; A reg-direct w/ depth-2
// ring; B from fragment-packed w1F/w2F (1KB coalesced wave loads).
// Outputs: rw natural split + rwF fragment-packed (for anchor).
// grid = 8b * 64 stiles(64 tok) = 512, 256 threads (4 waves)
// ---------------------------------------------------------------------------
__global__ __launch_bounds__(TB) void k_route(
    const float* __restrict__ x, const float* __restrict__ efas,
    const float* __restrict__ w_e, const float* __restrict__ b_e,
    const float* __restrict__ b1, const float* __restrict__ b2,
    const ushort* __restrict__ w1f_h, const ushort* __restrict__ w1f_l,
    const ushort* __restrict__ w2f_h, const ushort* __restrict__ w2f_l,
    ushort* __restrict__ rwh, ushort* __restrict__ rwl,
    ushort* __restrict__ rfh, ushort* __restrict__ rfl)
{
    __shared__ __align__(16) ushort hh_t[64*72], hl_t[64*72];
    const int tid = threadIdx.x, lane = tid & 63, wv = tid >> 6;
    const int r15 = lane & 15, gg = lane >> 4;
    const int b = blockIdx.x & 7, stile = blockIdx.x >> 3;
    const int t0 = stile * 64;
    const int tokrow = t0 + wv*16 + r15;

    const float* xr = &x[((size_t)b*Ss + tokrow)*Dd + gg*8];

    f32x4 acc[4];
#pragma unroll
    for (int nt = 0; nt < 4; ++nt) acc[nt] = (f32x4)0.f;

#define LDX(A,B,C,D,KC) { const float* q_ = xr + (KC)*64; \
    A = *(const float4*)q_; B = *(const float4*)(q_+4); \
    C = *(const float4*)(q_+32); D = *(const float4*)(q_+36); }

    float4 p0a,p0b,p0c,p0d, p1a,p1b,p1c,p1d;
    LDX(p0a,p0b,p0c,p0d, 0)
    LDX(p1a,p1b,p1c,p1d, 1)

    for (int kc2 = 0; kc2 < 8; ++kc2) {
        const int kc = kc2 * 2;
        {   // chunk kc (even) from p0*
            bf16x8 a0h,a0l,a1h,a1l;
            cvt8(p0a, p0b, a0h, a0l);
            cvt8(p0c, p0d, a1h, a1l);
            int kn = kc + 2 > 15 ? 15 : kc + 2;
            LDX(p0a,p0b,p0c,p0d, kn)
#pragma unroll
            for (int nt = 0; nt < 4; ++nt) {
                size_t w0 = ((size_t)(nt*16 + kc)*2 + 0)*512 + lane*8;
                size_t w1i = ((size_t)(nt*16 + kc)*2 + 1)*512 + lane*8;
                acc[nt] = mm3(a0h, a0l, *(const bf16x8*)&w1f_h[w0],
                              *(const bf16x8*)&w1f_l[w0], acc[nt]);
                acc[nt] = mm3(a1h, a1l, *(const bf16x8*)&w1f_h[w1i],
                              *(const bf16x8*)&w1f_l[w1i], acc[nt]);
            }
        }
        {   // chunk kc+1 (odd) from p1*
            bf16x8 a0h,a0l,a1h,a1l;
            cvt8(p1a, p1b, a0h, a0l);
            cvt8(p1c, p1d, a1h, a1l);
            int kn = kc + 3 > 15 ? 15 : kc + 3;
            LDX(p1a,p1b,p1c,p1d, kn)
#pragma unroll
            for (int nt = 0; nt < 4; ++nt) {
                size_t w0 = ((size_t)(nt*16 + kc+1)*2 + 0)*512 + lane*8;
                size_t w1i = ((size_t)(nt*16 + kc+1)*2 + 1)*512 + lane*8;
                acc[nt] = mm3(a0h, a0l, *(const bf16x8*)&w1f_h[w0],
                              *(const bf16x8*)&w1f_l[w0], acc[nt]);
                acc[nt] = mm3(a1h, a1l, *(const bf16x8*)&w1f_h[w1i],
                              *(const bf16x8*)&w1f_l[w1i], acc[nt]);
            }
        }
    }
#undef LDX

    // h = relu(acc+b1) -> per-wave LDS rows (no cross-wave sync needed)
#pragma unroll
    for (int nt = 0; nt < 4; ++nt) {
        float b1v = b1[nt*16 + r15];
#pragma unroll
        for (int j = 0; j < 4; ++j) {
            float hv = fmaxf(acc[nt][j] + b1v, 0.f);
            ushort hh, hl; split2(hv, hh, hl);
            st1(hh_t, wv*16 + gg*4 + j, nt*16 + r15, hh);
            st1(hl_t, wv*16 + gg*4 + j, nt*16 + r15, hl);
        }
    }
    // h @ w2 (fragment-packed)
    f32x4 a2[4];
#pragma unroll
    for (int nt = 0; nt < 4; ++nt) a2[nt] = (f32x4)0.f;
#pragma unroll
    for (int ks = 0; ks < 2; ++ks) {
        bf16x8 ah = ldfrag(hh_t, wv*16 + r15, ks*4 + gg);
        bf16x8 al = ldfrag(hl_t, wv*16 + r15, ks*4 + gg);
#pragma unroll
        for (int nt = 0; nt < 4; ++nt) {
            size_t wi = ((size_t)nt*2 + ks)*512 + lane*8;
            a2[nt] = mm3(ah, al, *(const bf16x8*)&w2f_h[wi],
                         *(const bf16x8*)&w2f_l[wi], a2[nt]);
        }
    }
    // logits + in-wave softmax over all 64 k
    float wev[4], bev[4], b2v[4];
#pragma unroll
    for (int nt = 0; nt < 4; ++nt) {
        wev[nt] = w_e[nt*16 + r15]; bev[nt] = b_e[nt*16 + r15]; b2v[nt] = b2[nt*16 + r15];
    }
    float pr[4][4];
#pragma unroll
    for (int j = 0; j < 4; ++j) {
        int row = t0 + wv*16 + gg*4 + j;
        float ef = efas[(size_t)b*Ss + row];
        float t[4];
#pragma unroll
        for (int nt = 0; nt < 4; ++nt)
            t[nt] = (a2[nt][j] + b2v[nt] + 2.f*(ef*wev[nt] + bev[nt])) * INV_TEMP;
        float m = fmaxf(fmaxf(t[0], t[1]), fmaxf(t[2], t[3]));
#pragma unroll
        for (int off = 1; off <= 8; off <<= 1) m = fmaxf(m, __shfl_xor(m, off));
        float s = 0.f;
#pragma unroll
        for (int nt = 0; nt < 4; ++nt) { t[nt] = __expf(t[nt] - m); s += t[nt]; }
#pragma unroll
        for (int off = 1; off <= 8; off <<= 1) s += __shfl_xor(s, off);
        float inv = 1.f / s;
#pragma unroll
        for (int nt = 0; nt < 4; ++nt) pr[j][nt] = t[nt] * inv;
    }
    // natural split write [b][s][64]
#pragma unroll
    for (int j = 0; j < 4; ++j) {
        int row = t0 + wv*16 + gg*4 + j;
#pragma unroll
        for (int nt = 0; nt < 4; ++nt) {
            ushort hh, hl; split2(pr[j][nt], hh, hl);
            size_t o = ((size_t)b*Ss + row)*Kk + nt*16 + r15;
            rwh[o] = hh; rwl[o] = hl;
        }
    }
    // fragment-packed rwF write: [b][stile][kt][ks][512u]
    {
        const int t_off = wv*16 + gg*4;            // token offset in stile
        const int ksf = t_off >> 5, ggaf = (t_off >> 3) & 3, half = (t_off >> 2) & 1;
#pragma unroll
        for (int nt = 0; nt < 4; ++nt) {
            ushort h0,h1,h2,h3,l0,l1,l2,l3;
            split2(pr[0][nt],h0,l0); split2(pr[1][nt],h1,l1);
            split2(pr[2][nt],h2,l2); split2(pr[3][nt],h3,l3);
            size_t o = (((size_t)b*64 + stile)*8 + nt*2 + ksf)*512
                     + (ggaf*16 + r15)*8 + half*4;
            *(ushort4*)&rfh[o] = make_ushort4(h0,h1,h2,h3);
            *(ushort4*)&rfl[o] = make_ushort4(l0,l1,l2,l3);
        }
    }
}

// ---------------------------------------------------------------------------
// k_anchor: ai[b,k,d] += sum_s rw[s,k]*x[s,d]
// A = rwF coalesced reg-direct; B = xT via double-buffered LDS with
// lgkm-only barriers + depth-2 register ring.
// grid = 8b * 16dt(64 d) * 8sc(512 s) = 1024
// ---------------------------------------------------------------------------
__global__ __launch_bounds__(TB) void k_anchor(
    const float* __restrict__ x, const ushort* __restrict__ rfh,
    const ushort* __restrict__ rfl, float* __restrict__ ai)
{
    __shared__ __align__(16) ushort bh0[64*72], bl0[64*72];
    __shared__ __align__(16) ushort bh1[64*72], bl1[64*72];
    const int tid = threadIdx.x, lane = tid & 63, wv = tid >> 6;
    const int r15 = lane & 15, gg = lane >> 4;
    const int b = blockIdx.x & 7, dt = (blockIdx.x >> 3) & 15, sc = blockIdx.x >> 7;

    const int d0 = (tid & 15) * 4, s0q = (tid >> 4) * 4;
    const float* xb0 = &x[((size_t)b*Ss + sc*512 + s0q)*Dd + dt*64 + d0];

    float4 rg[2][4];
#pragma unroll
    for (int r = 0; r < 4; ++r) rg[0][r] = *(const float4*)(xb0 + (size_t)r*Dd);
#pragma unroll
    for (int r = 0; r < 4; ++r) rg[1][r] = *(const float4*)(xb0 + (size_t)(64 + r)*Dd);
    trf(bh0, bl0, d0, s0q, rg[0][0], rg[0][1], rg[0][2], rg[0][3]);
    lds_barrier();

    f32x4 acc[4];
#pragma unroll
    for (int mt = 0; mt < 4; ++mt) acc[mt] = (f32x4)0.f;

#pragma unroll
    for (int cc = 0; cc < 8; ++cc) {
        const ushort* cbh = (cc & 1) ? bh1 : bh0;
        const ushort* cbl = (cc & 1) ? bl1 : bl0;
        if (cc < 7) {
            ushort* nbh = (cc & 1) ? bh0 : bh1;
            ushort* nbl = (cc & 1) ? bl0 : bl1;
            trf(nbh, nbl, d0, s0q, rg[(cc+1)&1][0], rg[(cc+1)&1][1],
                rg[(cc+1)&1][2], rg[(cc+1)&1][3]);
        }
        if (cc < 6) {
            const float* nb = xb0 + (size_t)(cc + 2) * 64 * Dd;
#pragma unroll
            for (int r = 0; r < 4; ++r) rg[cc&1][r] = *(const float4*)(nb + (size_t)r*Dd);
        }
#pragma unroll
        for (int ks = 0; ks < 2; ++ks) {
            bf16x8 xbh = ldfrag(cbh, wv*16 + r15, ks*4 + gg);
            bf16x8 xbl = ldfrag(cbl, wv*16 + r15, ks*4 + gg);
#pragma unroll
            for (int mt = 0; mt < 4; ++mt) {
                size_t ri = (((size_t)b*64 + sc*8 + cc)*8 + mt*2 + ks)*512 + lane*8;
                acc[mt] = mm3(*(const bf16x8*)&rfh[ri], *(const bf16x8*)&rfl[ri],
                              xbh, xbl, acc[mt]);
            }
        }
        lds_barrier();
    }
#pragma unroll
    for (int mt = 0; mt < 4; ++mt)
#pragma unroll
      for (int j = 0; j < 4; ++j) {
        int k = mt*16 + gg*4 + j;
        int d = dt*64 + wv*16 + r15;
        atomicAdd(&ai[((size_t)b*Kk + k)*Dd + d], acc[mt][j]);
      }
}

// ---------------------------------------------------------------------------
// k_cvt: ai fp32 -> split bf16 natural
// ---------------------------------------------------------------------------
__global__ __launch_bounds__(TB) void k_cvt(
    const float* __restrict__ ai, ushort* __restrict__ aih, ushort* __restrict__ ail)
{
    size_t i = ((size_t)blockIdx.x * TB + threadIdx.x) * 4;
    float4 v = *(const float4*)&ai[i];
    ushort h0,h1,h2,h3,l0,l1,l2,l3;
    split2(v.x,h0,l0); split2(v.y,h1,l1); split2(v.z,h2,l2); split2(v.w,h3,l3);
    *(ushort4*)&aih[i] = make_ushort4(h0,h1,h2,h3);
    *(ushort4*)&ail[i] = make_ushort4(l0,l1,l2,l3);
}

// ---------------------------------------------------------------------------
// k_gemm: C[b,64,NDIM] = A-split[b,64,1024] @ WT-split (+bias); reg-direct,
// n-tile 64 (1 ntile per wave). grid = 8 * NDIM/64
// ---------------------------------------------------------------------------
template <int NDIM, int EPI>
__global__ __launch_bounds__(TB) void k_gemm(
    const ushort* __restrict__ AH, const ushort* __restrict__ AL,
    const ushort* __restrict__ WH, const ushort* __restrict__ WL,
    const float* __restrict__ bias,
    ushort* __restrict__ OH, ushort* __restrict__ OL,
    ushort* __restrict__ TH, ushort* __restrict__ TL)
{
    const int tid = threadIdx.x, lane = tid & 63, wv = tid >> 6;
    const int r15 = lane & 15, gg = lane >> 4;
    constexpr int NT = NDIM / 64;
    const int b = blockIdx.x / NT, n0 = (blockIdx.x % NT) * 64;

    f32x4 acc[4];
#pragma unroll
    for (int mt = 0; mt < 4; ++mt) acc[mt] = (f32x4)0.f;

    for (int kc = 0; kc < 32; ++kc) {
        const int kb = kc * 32 + gg * 8;
        size_t widx = ((size_t)(n0 + wv*16 + r15))*Dd + kb;
        bf16x8 bh = *(const bf16x8*)&WH[widx];
        bf16x8 bl = *(const bf16x8*)&WL[widx];
#pragma unroll
        for (int mt = 0; mt < 4; ++mt) {
            size_t aidx = ((size_t)b*64 + mt*16 + r15)*Dd + kb;
            acc[mt] = mm3(*(const bf16x8*)&AH[aidx], *(const bf16x8*)&AL[aidx],
                          bh, bl, acc[mt]);
        }
    }
    const int n = n0 + wv*16 + r15;
    float bb = (EPI == 2) ? 0.f : bias[n];
#pragma unroll
    for (int mt = 0; mt < 4; ++mt) {
        if (EPI == 2 || (EPI == 1 && n0 >= 2048)) {
            ushort h[4], l[4];
#pragma unroll
            for (int j = 0; j < 4; ++j) split2(acc[mt][j] + bb, h[j], l[j]);
            int nn = (EPI == 1) ? n - 2048 : n;
            size_t o = ((size_t)b*Dd + nn)*64 + mt*16 + gg*4;
            *(ushort4*)&TH[o] = make_ushort4(h[0],h[1],h[2],h[3]);
            *(ushort4*)&TL[o] = make_ushort4(l[0],l[1],l[2],l[3]);
        } else {
            constexpr int OST = (EPI == 1) ? 2048 : 1024;
#pragma unroll
            for (int j = 0; j < 4; ++j) {
                ushort hh, hl; split2(acc[mt][j] + bb, hh, hl);
                size_t o = ((size_t)b*64 + mt*16 + gg*4 + j)*OST + n;
                OH[o] = hh; OL[o] = hl;
            }
        }
    }
}

// ---------------------------------------------------------------------------
// k_attn: per (b,h): scores (reg-direct Q,K), softmax, PV (reg-direct VT)
// grid = 64
// ---------------------------------------------------------------------------
__global__ __launch_bounds__(TB) void k_attn(
    const ushort* __restrict__ qkh, const ushort* __restrict__ qkl,
    const ushort* __restrict__ vth, const ushort* __restrict__ vtl,
    ushort* __restrict__ atth, ushort* __restrict__ attl)
{
    __shared__ __align__(16) ushort ph[64*72], pl[64*72];
    const int tid = threadIdx.x, lane = tid & 63, wv = tid >> 6;
    const int r15 = lane & 15, gg = lane >> 4;
    const int b = blockIdx.x >> 3, h = blockIdx.x & 7;

    f32x4 sc[4];
#pragma unroll
    for (int nt = 0; nt < 4; ++nt) sc[nt] = (f32x4)0.f;
#pragma unroll
    for (int kb = 0; kb < 4; ++kb) {
        size_t qi = ((size_t)b*64 + wv*16 + r15)*2048 + h*128 + kb*32 + gg*8;
        bf16x8 ah = *(const bf16x8*)&qkh[qi];
        bf16x8 al = *(const bf16x8*)&qkl[qi];
#pragma unroll
        for (int nt = 0; nt < 4; ++nt) {
            size_t ki = ((size_t)b*64 + nt*16 + r15)*2048 + 1024 + h*128 + kb*32 + gg*8;
            sc[nt] = mm3(ah, al, *(const bf16x8*)&qkh[ki],
                         *(const bf16x8*)&qkl[ki], sc[nt]);
        }
    }
    float pr[4][4];
#pragma unroll
    for (int j = 0; j < 4; ++j) {
        float t[4];
#pragma unroll
        for (int nt = 0; nt < 4; ++nt) t[nt] = sc[nt][j] * ATTN_SCALE;
        float m = fmaxf(fmaxf(t[0],t[1]), fmaxf(t[2],t[3]));
#pragma unroll
        for (int off = 1; off <= 8; off <<= 1) m = fmaxf(m, __shfl_xor(m, off));
        float s = 0.f;
#pragma unroll
        for (int nt = 0; nt < 4; ++nt) { t[nt] = __expf(t[nt] - m); s += t[nt]; }
#pragma unroll
        for (int off = 1; off <= 8; off <<= 1) s += __shfl_xor(s, off);
        float inv = 1.f / s;
#pragma unroll
        for (int nt = 0; nt < 4; ++nt) pr[j][nt] = t[nt] * inv;
    }
#pragma unroll
    for (int j = 0; j < 4; ++j)
#pragma unroll
      for (int nt = 0; nt < 4; ++nt) {
        ushort hh, hl; split2(pr[j][nt], hh, hl);
        st1(ph, wv*16 + gg*4 + j, nt*16 + r15, hh);
        st1(pl, wv*16 + gg*4 + j, nt*16 + r15, hl);
      }
    __syncthreads();
    f32x4 o[8];
#pragma unroll
    for (int nt = 0; nt < 8; ++nt) o[nt] = (f32x4)0.f;
#pragma unroll
    for (int ks = 0; ks < 2; ++ks) {
        bf16x8 ah = ldfrag(ph, wv*16 + r15, ks*4 + gg);
        bf16x8 al = ldfrag(pl, wv*16 + r15, ks*4 + gg);
#pragma unroll
        for (int nt = 0; nt < 8; ++nt) {
            size_t vi = ((size_t)b*Dd + h*128 + nt*16 + r15)*64 + ks*32 + gg*8;
            o[nt] = mm3(ah, al, *(const bf16x8*)&vth[vi],
                        *(const bf16x8*)&vtl[vi], o[nt]);
        }
    }
#pragma unroll
    for (int nt = 0; nt < 8; ++nt)
#pragma unroll
      for (int j = 0; j < 4; ++j) {
        ushort hh, hl; split2(o[nt][j], hh, hl);
        size_t oo = ((size_t)b*64 + wv*16 + gg*4 + j)*Dd + h*128 + nt*16 + r15;
        atth[oo] = hh; attl[oo] = hl;
      }
}

// ---------------------------------------------------------------------------
// k_scatter: out = rw @ aop + b_p  (reg-direct both sides, LDS-free)
// grid = 8b * 32st(128 tok) * 8dt(128 d) = 2048
// ---------------------------------------------------------------------------
__global__ __launch_bounds__(TB) void k_scatter(
    const ushort* __restrict__ rwh, const ushort* __restrict__ rwl,
    const ushort* __restrict__ aph, const ushort* __restrict__ apl,
    const float* __restrict__ b_p, float* __restrict__ out)
{
    const int tid = threadIdx.x, lane = tid & 63, wv = tid >> 6;
    const int r15 = lane & 15, gg = lane >> 4;
    const int b = blockIdx.x & 7, st = (blockIdx.x >> 3) & 31, dt = blockIdx.x >> 8;
    const int t0 = st * 128;

    f32x4 acc[2][8];
#pragma unroll
    for (int mt = 0; mt < 2; ++mt)
#pragma unroll
      for (int nt = 0; nt < 8; ++nt) acc[mt][nt] = (f32x4)0.f;

#pragma unroll
    for (int ks = 0; ks < 2; ++ks) {
        bf16x8 ah[2], al[2];
#pragma unroll
        for (int mt = 0; mt < 2; ++mt) {
            size_t ri = ((size_t)b*Ss + t0 + wv*32 + mt*16 + r15)*Kk + ks*32 + gg*8;
            ah[mt] = *(const bf16x8*)&rwh[ri];
            al[mt] = *(const bf16x8*)&rwl[ri];
        }
#pragma unroll
        for (int nt = 0; nt < 8; ++nt) {
            size_t bi = ((size_t)b*Dd + dt*128 + nt*16 + r15)*Kk + ks*32 + gg*8;
            bf16x8 bh = *(const bf16x8*)&aph[bi];
            bf16x8 bl = *(const bf16x8*)&apl[bi];
#pragma unroll
            for (int mt = 0; mt < 2; ++mt)
                acc[mt][nt] = mm3(ah[mt], al[mt], bh, bl, acc[mt][nt]);
        }
    }
#pragma unroll
    for (int nt = 0; nt < 8; ++nt) {
        float bp = b_p[dt*128 + nt*16 + r15];
#pragma unroll
        for (int mt = 0; mt < 2; ++mt)
#pragma unroll
          for (int j = 0; j < 4; ++j)
            out[((size_t)b*Ss + t0 + wv*32 + mt*16 + gg*4 + j)*Dd + dt*128 + nt*16 + r15]
                = acc[mt][nt][j] + bp;
    }
}

extern "C" void kernel_launch(void* const* d_in, const int* in_sizes, int n_in,
                              void* d_out, int out_size, void* d_ws, size_t ws_size,
                              hipStream_t stream)
{
    const float* x     = (const float*)d_in[0];
    const float* efas  = (const float*)d_in[1];
    const float* w_e   = (const float*)d_in[2];
    const float* b_e   = (const float*)d_in[3];
    const float* w1    = (const float*)d_in[4];
    const float* b1    = (const float*)d_in[5];
    const float* w2    = (const float*)d_in[6];
    const float* b2    = (const float*)d_in[7];
    const float* w_qkv = (const float*)d_in[8];
    const float* b_qkv = (const float*)d_in[9];
    const float* w_o   = (const float*)d_in[10];
    const float* b_o   = (const float*)d_in[11];
    const float* w_p   = (const float*)d_in[12];
    const float* b_p   = (const float*)d_in[13];
    float* out = (float*)d_out;
    char* ws = (char*)d_ws;

    ushort* w1h = (ushort*)(ws + OFF_W1H); ushort* w1l = (ushort*)(ws + OFF_W1L);
    ushort* w2h = (ushort*)(ws + OFF_W2H); ushort* w2l = (ushort*)(ws + OFF_W2L);
    ushort* wqh = (ushort*)(ws + OFF_WQH); ushort* wql = (ushort*)(ws + OFF_WQL);
    ushort* woh = (ushort*)(ws + OFF_WOH); ushort* wol = (ushort*)(ws + OFF_WOL);
    ushort* wph = (ushort*)(ws + OFF_WPH); ushort* wpl = (ushort*)(ws + OFF_WPL);
    ushort* rwh = (ushort*)(ws + OFF_RWH); ushort* rwl = (ushort*)(ws + OFF_RWL);
    float*  aif = (float*) (ws + OFF_AIF);
    ushort* aih = (ushort*)(ws + OFF_AIH); ushort* ail = (ushort*)(ws + OFF_AIL);
    ushort* rfh = (ushort*)(ws + OFF_RFH); ushort* rfl = (ushort*)(ws + OFF_RFL);
    ushort* qkh = (ushort*)(ws + OFF_QKH); ushort* qkl = (ushort*)(ws + OFF_QKL);
    ushort* vth = (ushort*)(ws + OFF_VTH); ushort* vtl = (ushort*)(ws + OFF_VTL);
    ushort* ath = (ushort*)(ws + OFF_ATH); ushort* atl = (ushort*)(ws + OFF_ATL);
    ushort* aoh = (ushort*)(ws + OFF_AOH); ushort* aol = (ushort*)(ws + OFF_AOL);
    ushort* aph = (ushort*)(ws + OFF_APH); ushort* apl = (ushort*)(ws + OFF_APL);

    hipLaunchKernelGGL(k_prep, dim3(1297), dim3(TB), 0, stream,
                       w1, w2, w_qkv, w_o, w_p,
                       w1h, w1l, w2h, w2l, wqh, wql, woh, wol, wph, wpl);
    hipLaunchKernelGGL(k_zero, dim3(512), dim3(TB), 0, stream,
                       aif, (int)(SZ_AIF / 16));
    hipLaunchKernelGGL(k_route, dim3(512), dim3(TB), 0, stream,
                       x, efas, w_e, b_e, b1, b2, w1h, w1l, w2h, w2l,
                       rwh, rwl, rfh, rfl);
    hipLaunchKernelGGL(k_anchor, dim3(1024), dim3(TB), 0, stream, x, rfh, rfl, aif);
    hipLaunchKernelGGL(k_cvt, dim3(512), dim3(TB), 0, stream, aif, aih, ail);
    hipLaunchKernelGGL((k_gemm<3072, 1>), dim3(384), dim3(TB), 0, stream,
                       aih, ail, wqh, wql, b_qkv, qkh, qkl, vth, vtl);
    hipLaunchKernelGGL(k_attn, dim3(64), dim3(TB), 0, stream,
                       qkh, qkl, vth, vtl, ath, atl);
    hipLaunchKernelGGL((k_gemm<1024, 0>), dim3(128), dim3(TB), 0, stream,
                       ath, atl, woh, wol, b_o, aoh, aol,
                       (ushort*)nullptr, (ushort*)nullptr);
    hipLaunchKernelGGL((k_gemm<1024, 2>), dim3(128), dim3(TB), 0, stream,
                       aoh, aol, wph, wpl, (const float*)nullptr,
                       (ushort*)nullptr, (ushort*)nullptr, aph, apl);
    hipLaunchKernelGGL(k_scatter, dim3(2048), dim3(TB), 0, stream,
                       rwh, rwl, aph, apl, b_p, out);
}

// Round 7
// 353.934 us; speedup vs baseline: 1.1585x; 1.1191x over previous
//
#include <hip/hip_runtime.h>
#include <cstddef>

#define TB 256

constexpr int Bb = 8, Ss = 4096, Dd = 1024, Kk = 64, Hh = 8;
constexpr float INV_TEMP = 10.0f;
constexpr float ATTN_SCALE = 0.08838834764831845f; // 1/sqrt(128)

typedef __attribute__((ext_vector_type(8))) short bf16x8;
typedef __attribute__((ext_vector_type(4))) float f32x4;

#define MFMA(a, b, c) __builtin_amdgcn_mfma_f32_16x16x32_bf16(a, b, c, 0, 0, 0)

// async global->LDS, 16B per lane; LDS dest must be wave-uniform base (+lane*16)
#define GLOAD16(gsrc, ldst) \
    __builtin_amdgcn_global_load_lds( \
        (const __attribute__((address_space(1))) unsigned int*)(gsrc), \
        (__attribute__((address_space(3))) unsigned int*)(ldst), 16, 0, 0)

// ---------------- workspace layout (bytes) ----------------
constexpr size_t SZ_W1  = (size_t)Kk*Dd*2;        // w1F fragment-packed
constexpr size_t SZ_W2  = (size_t)Kk*Kk*2;        // w2F fragment-packed
constexpr size_t SZ_WQ  = (size_t)3*Dd*Dd*2;
constexpr size_t SZ_WD  = (size_t)Dd*Dd*2;
constexpr size_t SZ_RW  = (size_t)Bb*Ss*Kk*2;
constexpr size_t SZ_AIF = (size_t)Bb*Kk*Dd*4;
constexpr size_t SZ_AI2 = (size_t)Bb*Kk*Dd*2;
constexpr size_t SZ_QK  = (size_t)Bb*Kk*2048*2;
constexpr size_t SZ_VT  = (size_t)Bb*Dd*Kk*2;
constexpr size_t SZ_AT  = (size_t)Bb*Kk*Dd*2;

constexpr size_t OFF_W1H = 0;
constexpr size_t OFF_W1L = OFF_W1H + SZ_W1;
constexpr size_t OFF_W2H = OFF_W1L + SZ_W1;
constexpr size_t OFF_W2L = OFF_W2H + SZ_W2;
constexpr size_t OFF_WQH = OFF_W2L + SZ_W2;
constexpr size_t OFF_WQL = OFF_WQH + SZ_WQ;
constexpr size_t OFF_WOH = OFF_WQL + SZ_WQ;
constexpr size_t OFF_WOL = OFF_WOH + SZ_WD;
constexpr size_t OFF_WPH = OFF_WOL + SZ_WD;
constexpr size_t OFF_WPL = OFF_WPH + SZ_WD;
constexpr size_t OFF_RWH = OFF_WPL + SZ_WD;       // rw natural split [b][s][64]
constexpr size_t OFF_RWL = OFF_RWH + SZ_RW;
constexpr size_t OFF_AIF = OFF_RWL + SZ_RW;
constexpr size_t OFF_AIH = OFF_AIF + SZ_AIF;
constexpr size_t OFF_AIL = OFF_AIH + SZ_AI2;
constexpr size_t OFF_U   = OFF_AIL + SZ_AI2;
// union phase 1: rwF fragment-packed [b][stile64][kt4][ks2][512u]
constexpr size_t OFF_RFH = OFF_U;
constexpr size_t OFF_RFL = OFF_U + SZ_RW;
// union phase 2: anchor-space tensors
constexpr size_t OFF_QKH = OFF_U;
constexpr size_t OFF_QKL = OFF_QKH + SZ_QK;
constexpr size_t OFF_VTH = OFF_QKL + SZ_QK;
constexpr size_t OFF_VTL = OFF_VTH + SZ_VT;
constexpr size_t OFF_ATH = OFF_VTL + SZ_VT;
constexpr size_t OFF_ATL = OFF_ATH + SZ_AT;
constexpr size_t OFF_AOH = OFF_ATL + SZ_AT;
constexpr size_t OFF_AOL = OFF_AOH + SZ_AT;
constexpr size_t OFF_APH = OFF_AOL + SZ_AT;
constexpr size_t OFF_APL = OFF_APH + SZ_AT;

// ---------------- scalar helpers ----------------
__device__ inline ushort f2bf(float f) {
    union { float f; uint u; } v; v.f = f;
    return (ushort)((v.u + 0x7fffu + ((v.u >> 16) & 1u)) >> 16);
}
__device__ inline float bf2f(ushort h) {
    union { uint u; float f; } v; v.u = ((uint)h) << 16;
    return v.f;
}
__device__ inline void split2(float f, ushort& h, ushort& l) {
    h = f2bf(f);
    l = f2bf(f - bf2f(h));
}
__device__ inline void cvt8(float4 a, float4 b, bf16x8& h8, bf16x8& l8) {
    float f[8] = {a.x, a.y, a.z, a.w, b.x, b.y, b.z, b.w};
#pragma unroll
    for (int i = 0; i < 8; ++i) {
        ushort hh, ll; split2(f[i], hh, ll);
        h8[i] = (short)hh; l8[i] = (short)ll;
    }
}
__device__ inline f32x4 mm3(bf16x8 ah, bf16x8 al, bf16x8 bh, bf16x8 bl, f32x4 c) {
    c = MFMA(ah, bh, c);
    c = MFMA(ah, bl, c);
    c = MFMA(al, bh, c);
    return c;
}

// ---- swizzled LDS bf16 tile, logical [row][64] (stride 72 ushorts = 144B) ---
__device__ inline void st1(ushort* t, int row, int s, ushort v) {
    char* p = (char*)t + row * 144 + ((((s >> 3) ^ ((row >> 2) & 7)) << 4) | ((s & 7) << 1));
    *(ushort*)p = v;
}
__device__ inline bf16x8 ldfrag(const ushort* t, int row, int sblk) {
    const char* p = (const char*)t + row * 144 + (((sblk ^ ((row >> 2) & 7))) << 4);
    return *(const bf16x8*)p;
}

__global__ __launch_bounds__(TB) void k_zero(float* __restrict__ p, int n4) {
    int i = blockIdx.x * TB + threadIdx.x;
    if (i < n4) ((float4*)p)[i] = make_float4(0.f, 0.f, 0.f, 0.f);
}

// ---------------------------------------------------------------------------
// k_prep: w1/w2 -> fragment-major split blocks; wq/wo/wp -> [out][in] split
// ---------------------------------------------------------------------------
__global__ __launch_bounds__(TB) void k_prep(
    const float* __restrict__ w1, const float* __restrict__ w2,
    const float* __restrict__ wq, const float* __restrict__ wo,
    const float* __restrict__ wp,
    ushort* __restrict__ w1h, ushort* __restrict__ w1l,
    ushort* __restrict__ w2h, ushort* __restrict__ w2l,
    ushort* __restrict__ wqh, ushort* __restrict__ wql,
    ushort* __restrict__ woh, ushort* __restrict__ wol,
    ushort* __restrict__ wph, ushort* __restrict__ wpl)
{
    __shared__ float t[64][64];
    const int blk = blockIdx.x, tid = threadIdx.x;
    const float* in; ushort* oh; ushort* ol; int R, IC, r0, c0, mode;
    if (blk < 16)        { in = w1; oh = w1h; ol = w1l; R = 1024; IC = 64;
                           r0 = blk * 64; c0 = 0; mode = 1; }
    else if (blk == 16)  { in = w2; oh = w2h; ol = w2l; R = 64;   IC = 64;
                           r0 = 0; c0 = 0; mode = 2; }
    else if (blk < 785)  { int i = blk - 17; in = wq; oh = wqh; ol = wql;
                           R = 1024; IC = 3072; r0 = (i / 48) * 64; c0 = (i % 48) * 64; mode = 0; }
    else if (blk < 1041) { int i = blk - 785; in = wo; oh = woh; ol = wol;
                           R = 1024; IC = 1024; r0 = (i / 16) * 64; c0 = (i % 16) * 64; mode = 0; }
    else                 { int i = blk - 1041; in = wp; oh = wph; ol = wpl;
                           R = 1024; IC = 1024; r0 = (i / 16) * 64; c0 = (i % 16) * 64; mode = 0; }
    {
        int r = tid >> 2, cq = (tid & 3) * 16;
        const float* ip = &in[(size_t)(r0 + r) * IC + c0 + cq];
#pragma unroll
        for (int q = 0; q < 4; ++q)
            *(float4*)&t[r][cq + q * 4] = *(const float4*)(ip + q * 4);
    }
    __syncthreads();
    {
        int oc = tid & 63, or0 = (tid >> 6) * 16;
        ushort th[16], tl[16];
#pragma unroll
        for (int i = 0; i < 16; ++i) split2(t[or0 + i][oc], th[i], tl[i]);
        if (mode == 0) {
            size_t base = (size_t)(c0 + oc) * R + r0 + or0;
#pragma unroll
            for (int q = 0; q < 4; ++q) {
                *(ushort4*)&oh[base + q*4] = make_ushort4(th[q*4], th[q*4+1], th[q*4+2], th[q*4+3]);
                *(ushort4*)&ol[base + q*4] = make_ushort4(tl[q*4], tl[q*4+1], tl[q*4+2], tl[q*4+3]);
            }
        } else {
            int nt = oc >> 4, r15o = oc & 15;
#pragma unroll
            for (int ii = 0; ii < 16; ++ii) {
                int i = or0 + ii;
                int ks = i >> 5, gga = (i >> 3) & 3, el = i & 7;
                size_t idx = (mode == 1)
                    ? (((size_t)(nt*16 + blk)*2 + ks)*512 + (gga*16 + r15o)*8 + el)
                    : (((size_t)nt*2 + ks)*512 + (gga*16 + r15o)*8 + el);
                oh[idx] = th[ii]; ol[idx] = tl[ii];
            }
        }
    }
}

// ---------------------------------------------------------------------------
// k_route: m97-style. x fp32 chunks [128 tok][64 d] staged async via
// global_load_lds into 2x32KB LDS dbuf, pre-swizzled source (slot^=row&15).
// Convert to split-bf16 at fragment read; B = fragment-packed w1F/w2F.
// grid = 8b * 32 stiles(128 tok) = 256, 256 threads (4 waves)
// ---------------------------------------------------------------------------
__global__ __launch_bounds__(TB) void k_route(
    const float* __restrict__ x, const float* __restrict__ efas,
    const float* __restrict__ w_e, const float* __restrict__ b_e,
    const float* __restrict__ b1, const float* __restrict__ b2,
    const ushort* __restrict__ w1f_h, const ushort* __restrict__ w1f_l,
    const ushort* __restrict__ w2f_h, const ushort* __restrict__ w2f_l,
    ushort* __restrict__ rwh, ushort* __restrict__ rwl,
    ushort* __restrict__ rfh, ushort* __restrict__ rfl)
{
    __shared__ __align__(16) char smem[65536];
    float* xb0 = (float*)smem;
    float* xb1 = (float*)(smem + 32768);
    const int tid = threadIdx.x, lane = tid & 63, wv = tid >> 6;
    const int r15 = lane & 15, gg = lane >> 4;
    const int b = blockIdx.x & 7, st128 = blockIdx.x >> 3;
    const int t0 = st128 * 128;
    const size_t xbase = ((size_t)b*Ss + t0) * Dd;

    // stage chunk kc into buf: 8 gload16/thread; per-lane swizzled source
    auto stage = [&](int kc, float* buf) {
#pragma unroll
        for (int i = 0; i < 8; ++i) {
            int L = i*256 + wv*64 + lane;
            int row = L >> 4, slot = L & 15;
            const float* src = &x[xbase + (size_t)row*Dd + kc*64 + ((slot ^ (row & 15)) << 2)];
            GLOAD16(src, (char*)buf + i*4096 + wv*1024);
        }
    };

    f32x4 acc[2][4];
#pragma unroll
    for (int mt = 0; mt < 2; ++mt)
#pragma unroll
      for (int nt = 0; nt < 4; ++nt) acc[mt][nt] = (f32x4)0.f;

    stage(0, xb0);
    __syncthreads();

    for (int kc = 0; kc < 16; ++kc) {
        if (kc < 15) stage(kc + 1, (kc & 1) ? xb0 : xb1);
        const float* xbf = (kc & 1) ? xb1 : xb0;
        // A fragments: rows wv*32+mt*16+r15, floats ks*32+gg*8 (swizzled slots)
        bf16x8 ah[2][2], al[2][2];
#pragma unroll
        for (int mt = 0; mt < 2; ++mt) {
            int row = wv*32 + mt*16 + r15;
            int rm = row & 15;
#pragma unroll
            for (int ks = 0; ks < 2; ++ks) {
                int slot0 = ks*8 + gg*2;
                float4 va = *(const float4*)&xbf[row*64 + (((slot0    ) ^ rm) << 2)];
                float4 vb = *(const float4*)&xbf[row*64 + (((slot0 + 1) ^ rm) << 2)];
                cvt8(va, vb, ah[mt][ks], al[mt][ks]);
            }
        }
#pragma unroll
        for (int nt = 0; nt < 4; ++nt) {
#pragma unroll
            for (int ks = 0; ks < 2; ++ks) {
                size_t wi = ((size_t)(nt*16 + kc)*2 + ks)*512 + lane*8;
                bf16x8 bh = *(const bf16x8*)&w1f_h[wi];
                bf16x8 bl = *(const bf16x8*)&w1f_l[wi];
#pragma unroll
                for (int mt = 0; mt < 2; ++mt)
                    acc[mt][nt] = mm3(ah[mt][ks], al[mt][ks], bh, bl, acc[mt][nt]);
            }
        }
        __syncthreads();
    }

    // h = relu(acc+b1) -> swizzled split tiles (overlay on smem)
    ushort* hh_t = (ushort*)smem;             // [128][72] = 18.4 KB
    ushort* hl_t = (ushort*)(smem + 20480);   // [128][72]
    __syncthreads();
#pragma unroll
    for (int mt = 0; mt < 2; ++mt)
#pragma unroll
      for (int nt = 0; nt < 4; ++nt) {
        float b1v = b1[nt*16 + r15];
#pragma unroll
        for (int j = 0; j < 4; ++j) {
            float hv = fmaxf(acc[mt][nt][j] + b1v, 0.f);
            ushort hh, hl; split2(hv, hh, hl);
            st1(hh_t, wv*32 + mt*16 + gg*4 + j, nt*16 + r15, hh);
            st1(hl_t, wv*32 + mt*16 + gg*4 + j, nt*16 + r15, hl);
        }
      }
    // h @ w2 (per-wave rows only; same-wave LDS RAW is safe)
    f32x4 a2[2][4];
#pragma unroll
    for (int mt = 0; mt < 2; ++mt)
#pragma unroll
      for (int nt = 0; nt < 4; ++nt) a2[mt][nt] = (f32x4)0.f;
#pragma unroll
    for (int ks = 0; ks < 2; ++ks) {
        bf16x8 ah[2], al[2];
#pragma unroll
        for (int mt = 0; mt < 2; ++mt) {
            ah[mt] = ldfrag(hh_t, wv*32 + mt*16 + r15, ks*4 + gg);
            al[mt] = ldfrag(hl_t, wv*32 + mt*16 + r15, ks*4 + gg);
        }
#pragma unroll
        for (int nt = 0; nt < 4; ++nt) {
            size_t wi = ((size_t)nt*2 + ks)*512 + lane*8;
            bf16x8 bh = *(const bf16x8*)&w2f_h[wi];
            bf16x8 bl = *(const bf16x8*)&w2f_l[wi];
#pragma unroll
            for (int mt = 0; mt < 2; ++mt)
                a2[mt][nt] = mm3(ah[mt], al[mt], bh, bl, a2[mt][nt]);
        }
    }
    // logits + in-wave softmax, outputs
    float wev[4], bev[4], b2v[4];
#pragma unroll
    for (int nt = 0; nt < 4; ++nt) {
        wev[nt] = w_e[nt*16 + r15]; bev[nt] = b_e[nt*16 + r15]; b2v[nt] = b2[nt*16 + r15];
    }
#pragma unroll
    for (int mt = 0; mt < 2; ++mt) {
        float pr[4][4];
#pragma unroll
        for (int j = 0; j < 4; ++j) {
            int row = t0 + wv*32 + mt*16 + gg*4 + j;
            float ef = efas[(size_t)b*Ss + row];
            float t[4];
#pragma unroll
            for (int nt = 0; nt < 4; ++nt)
                t[nt] = (a2[mt][nt][j] + b2v[nt] + 2.f*(ef*wev[nt] + bev[nt])) * INV_TEMP;
            float m = fmaxf(fmaxf(t[0], t[1]), fmaxf(t[2], t[3]));
#pragma unroll
            for (int off = 1; off <= 8; off <<= 1) m = fmaxf(m, __shfl_xor(m, off));
            float s = 0.f;
#pragma unroll
            for (int nt = 0; nt < 4; ++nt) { t[nt] = __expf(t[nt] - m); s += t[nt]; }
#pragma unroll
            for (int off = 1; off <= 8; off <<= 1) s += __shfl_xor(s, off);
            float inv = 1.f / s;
#pragma unroll
            for (int nt = 0; nt < 4; ++nt) pr[j][nt] = t[nt] * inv;
        }
        // natural split write [b][s][64]
#pragma unroll
        for (int j = 0; j < 4; ++j) {
            int row = t0 + wv*32 + mt*16 + gg*4 + j;
#pragma unroll
            for (int nt = 0; nt < 4; ++nt) {
                ushort hh, hl; split2(pr[j][nt], hh, hl);
                size_t o = ((size_t)b*Ss + row)*Kk + nt*16 + r15;
                rwh[o] = hh; rwl[o] = hl;
            }
        }
        // fragment-packed rwF write: [b][stile64][kt][ks][512u]
        {
            const int t_off = wv*32 + mt*16 + gg*4;       // 0..124 within 128-blk
            const int stile = st128*2 + (t_off >> 6);
            const int t64 = t_off & 63;
            const int ksf = t64 >> 5, ggaf = (t64 >> 3) & 3, half = (t64 >> 2) & 1;
#pragma unroll
            for (int nt = 0; nt < 4; ++nt) {
                ushort h0,h1,h2,h3,l0,l1,l2,l3;
                split2(pr[0][nt],h0,l0); split2(pr[1][nt],h1,l1);
                split2(pr[2][nt],h2,l2); split2(pr[3][nt],h3,l3);
                size_t o = (((size_t)b*64 + stile)*8 + nt*2 + ksf)*512
                         + (ggaf*16 + r15)*8 + half*4;
                *(ushort4*)&rfh[o] = make_ushort4(h0,h1,h2,h3);
                *(ushort4*)&rfl[o] = make_ushort4(l0,l1,l2,l3);
            }
        }
    }
}

// ---------------------------------------------------------------------------
// k_anchor: ai[b,k,d] += sum_s rw[s,k]*x[s,d]
// A = rwF coalesced reg-direct; B = x fp32 tile [64s][64d] staged async via
// global_load_lds (linear), column-read (8x ds_read_b32) + cvt.
// grid = 8b * 16dt(64 d) * 8sc(512 s) = 1024
// ---------------------------------------------------------------------------
__global__ __launch_bounds__(TB) void k_anchor(
    const float* __restrict__ x, const ushort* __restrict__ rfh,
    const ushort* __restrict__ rfl, float* __restrict__ ai)
{
    __shared__ __align__(16) float xb[2][64*64];
    const int tid = threadIdx.x, lane = tid & 63, wv = tid >> 6;
    const int r15 = lane & 15, gg = lane >> 4;
    const int b = blockIdx.x & 7, dt = (blockIdx.x >> 3) & 15, sc = blockIdx.x >> 7;
    const int dcol = wv*16 + r15;

    auto stage = [&](int cc, float* buf) {
#pragma unroll
        for (int i = 0; i < 4; ++i) {
            int L = i*256 + wv*64 + lane;
            int row = L >> 4, slot = L & 15;
            const float* src = &x[((size_t)b*Ss + sc*512 + cc*64 + row)*Dd + dt*64 + (slot << 2)];
            GLOAD16(src, (char*)buf + i*4096 + wv*1024);
        }
    };

    f32x4 acc[4];
#pragma unroll
    for (int mt = 0; mt < 4; ++mt) acc[mt] = (f32x4)0.f;

    stage(0, xb[0]);
    __syncthreads();

    for (int cc = 0; cc < 8; ++cc) {
        if (cc < 7) stage(cc + 1, xb[(cc + 1) & 1]);
        const float* xbf = xb[cc & 1];
#pragma unroll
        for (int ks = 0; ks < 2; ++ks) {
            // B fragment: row n = dcol, s-values ks*32+gg*8..+7 (column read)
            float f0[4], f1[4];
#pragma unroll
            for (int e = 0; e < 4; ++e) f0[e] = xbf[(ks*32 + gg*8 + e)*64 + dcol];
#pragma unroll
            for (int e = 0; e < 4; ++e) f1[e] = xbf[(ks*32 + gg*8 + 4 + e)*64 + dcol];
            bf16x8 bh, bl;
            cvt8(make_float4(f0[0], f0[1], f0[2], f0[3]),
                 make_float4(f1[0], f1[1], f1[2], f1[3]), bh, bl);
#pragma unroll
            for (int mt = 0; mt < 4; ++mt) {
                size_t ri = (((size_t)b*64 + sc*8 + cc)*8 + mt*2 + ks)*512 + lane*8;
                acc[mt] = mm3(*(const bf16x8*)&rfh[ri], *(const bf16x8*)&rfl[ri],
                              bh, bl, acc[mt]);
            }
        }
        __syncthreads();
    }
#pragma unroll
    for (int mt = 0; mt < 4; ++mt)
#pragma unroll
      for (int j = 0; j < 4; ++j) {
        int k = mt*16 + gg*4 + j;
        int d = dt*64 + dcol;
        atomicAdd(&ai[((size_t)b*Kk + k)*Dd + d], acc[mt][j]);
      }
}

// ---------------------------------------------------------------------------
// k_cvt: ai fp32 -> split bf16 natural
// ---------------------------------------------------------------------------
__global__ __launch_bounds__(TB) void k_cvt(
    const float* __restrict__ ai, ushort* __restrict__ aih, ushort* __restrict__ ail)
{
    size_t i = ((size_t)blockIdx.x * TB + threadIdx.x) * 4;
    float4 v = *(const float4*)&ai[i];
    ushort h0,h1,h2,h3,l0,l1,l2,l3;
    split2(v.x,h0,l0); split2(v.y,h1,l1); split2(v.z,h2,l2); split2(v.w,h3,l3);
    *(ushort4*)&aih[i] = make_ushort4(h0,h1,h2,h3);
    *(ushort4*)&ail[i] = make_ushort4(l0,l1,l2,l3);
}

// ---------------------------------------------------------------------------
// k_gemm: C[b,64,NDIM] = A-split[b,64,1024] @ WT-split (+bias); reg-direct,
// n-tile 64 (1 ntile per wave). grid = 8 * NDIM/64
// ---------------------------------------------------------------------------
template <int NDIM, int EPI>
__global__ __launch_bounds__(TB) void k_gemm(
    const ushort* __restrict__ AH, const ushort* __restrict__ AL,
    const ushort* __restrict__ WH, const ushort* __restrict__ WL,
    const float* __restrict__ bias,
    ushort* __restrict__ OH, ushort* __restrict__ OL,
    ushort* __restrict__ TH, ushort* __restrict__ TL)
{
    const int tid = threadIdx.x, lane = tid & 63, wv = tid >> 6;
    const int r15 = lane & 15, gg = lane >> 4;
    constexpr int NT = NDIM / 64;
    const int b = blockIdx.x / NT, n0 = (blockIdx.x % NT) * 64;

    f32x4 acc[4];
#pragma unroll
    for (int mt = 0; mt < 4; ++mt) acc[mt] = (f32x4)0.f;

    for (int kc = 0; kc < 32; ++kc) {
        const int kb = kc * 32 + gg * 8;
        size_t widx = ((size_t)(n0 + wv*16 + r15))*Dd + kb;
        bf16x8 bh = *(const bf16x8*)&WH[widx];
        bf16x8 bl = *(const bf16x8*)&WL[widx];
#pragma unroll
        for (int mt = 0; mt < 4; ++mt) {
            size_t aidx = ((size_t)b*64 + mt*16 + r15)*Dd + kb;
            acc[mt] = mm3(*(const bf16x8*)&AH[aidx], *(const bf16x8*)&AL[aidx],
                          bh, bl, acc[mt]);
        }
    }
    const int n = n0 + wv*16 + r15;
    float bb = (EPI == 2) ? 0.f : bias[n];
#pragma unroll
    for (int mt = 0; mt < 4; ++mt) {
        if (EPI == 2 || (EPI == 1 && n0 >= 2048)) {
            ushort h[4], l[4];
#pragma unroll
            for (int j = 0; j < 4; ++j) split2(acc[mt][j] + bb, h[j], l[j]);
            int nn = (EPI == 1) ? n - 2048 : n;
            size_t o = ((size_t)b*Dd + nn)*64 + mt*16 + gg*4;
            *(ushort4*)&TH[o] = make_ushort4(h[0],h[1],h[2],h[3]);
            *(ushort4*)&TL[o] = make_ushort4(l[0],l[1],l[2],l[3]);
        } else {
            constexpr int OST = (EPI == 1) ? 2048 : 1024;
#pragma unroll
            for (int j = 0; j < 4; ++j) {
                ushort hh, hl; split2(acc[mt][j] + bb, hh, hl);
                size_t o = ((size_t)b*64 + mt*16 + gg*4 + j)*OST + n;
                OH[o] = hh; OL[o] = hl;
            }
        }
    }
}

// ---------------------------------------------------------------------------
// k_attn: per (b,h): scores (reg-direct Q,K), softmax, PV (reg-direct VT)
// grid = 64
// ---------------------------------------------------------------------------
__global__ __launch_bounds__(TB) void k_attn(
    const ushort* __restrict__ qkh, const ushort* __restrict__ qkl,
    const ushort* __restrict__ vth, const ushort* __restrict__ vtl,
    ushort* __restrict__ atth, ushort* __restrict__ attl)
{
    __shared__ __align__(16) ushort ph[64*72], pl[64*72];
    const int tid = threadIdx.x, lane = tid & 63, wv = tid >> 6;
    const int r15 = lane & 15, gg = lane >> 4;
    const int b = blockIdx.x >> 3, h = blockIdx.x & 7;

    f32x4 sc[4];
#pragma unroll
    for (int nt = 0; nt < 4; ++nt) sc[nt] = (f32x4)0.f;
#pragma unroll
    for (int kb = 0; kb < 4; ++kb) {
        size_t qi = ((size_t)b*64 + wv*16 + r15)*2048 + h*128 + kb*32 + gg*8;
        bf16x8 ah = *(const bf16x8*)&qkh[qi];
        bf16x8 al = *(const bf16x8*)&qkl[qi];
#pragma unroll
        for (int nt = 0; nt < 4; ++nt) {
            size_t ki = ((size_t)b*64 + nt*16 + r15)*2048 + 1024 + h*128 + kb*32 + gg*8;
            sc[nt] = mm3(ah, al, *(const bf16x8*)&qkh[ki],
                         *(const bf16x8*)&qkl[ki], sc[nt]);
        }
    }
    float pr[4][4];
#pragma unroll
    for (int j = 0; j < 4; ++j) {
        float t[4];
#pragma unroll
        for (int nt = 0; nt < 4; ++nt) t[nt] = sc[nt][j] * ATTN_SCALE;
        float m = fmaxf(fmaxf(t[0],t[1]), fmaxf(t[2],t[3]));
#pragma unroll
        for (int off = 1; off <= 8; off <<= 1) m = fmaxf(m, __shfl_xor(m, off));
        float s = 0.f;
#pragma unroll
        for (int nt = 0; nt < 4; ++nt) { t[nt] = __expf(t[nt] - m); s += t[nt]; }
#pragma unroll
        for (int off = 1; off <= 8; off <<= 1) s += __shfl_xor(s, off);
        float inv = 1.f / s;
#pragma unroll
        for (int nt = 0; nt < 4; ++nt) pr[j][nt] = t[nt] * inv;
    }
#pragma unroll
    for (int j = 0; j < 4; ++j)
#pragma unroll
      for (int nt = 0; nt < 4; ++nt) {
        ushort hh, hl; split2(pr[j][nt], hh, hl);
        st1(ph, wv*16 + gg*4 + j, nt*16 + r15, hh);
        st1(pl, wv*16 + gg*4 + j, nt*16 + r15, hl);
      }
    __syncthreads();
    f32x4 o[8];
#pragma unroll
    for (int nt = 0; nt < 8; ++nt) o[nt] = (f32x4)0.f;
#pragma unroll
    for (int ks = 0; ks < 2; ++ks) {
        bf16x8 ah = ldfrag(ph, wv*16 + r15, ks*4 + gg);
        bf16x8 al = ldfrag(pl, wv*16 + r15, ks*4 + gg);
#pragma unroll
        for (int nt = 0; nt < 8; ++nt) {
            size_t vi = ((size_t)b*Dd + h*128 + nt*16 + r15)*64 + ks*32 + gg*8;
            o[nt] = mm3(ah, al, *(const bf16x8*)&vth[vi],
                        *(const bf16x8*)&vtl[vi], o[nt]);
        }
    }
#pragma unroll
    for (int nt = 0; nt < 8; ++nt)
#pragma unroll
      for (int j = 0; j < 4; ++j) {
        ushort hh, hl; split2(o[nt][j], hh, hl);
        size_t oo = ((size_t)b*64 + wv*16 + gg*4 + j)*Dd + h*128 + nt*16 + r15;
        atth[oo] = hh; attl[oo] = hl;
      }
}

// ---------------------------------------------------------------------------
// k_scatter: out = rw @ aop + b_p  (reg-direct both sides, LDS-free)
// grid = 8b * 32st(128 tok) * 8dt(128 d) = 2048
// ---------------------------------------------------------------------------
__global__ __launch_bounds__(TB) void k_scatter(
    const ushort* __restrict__ rwh, const ushort* __restrict__ rwl,
    const ushort* __restrict__ aph, const ushort* __restrict__ apl,
    const float* __restrict__ b_p, float* __restrict__ out)
{
    const int tid = threadIdx.x, lane = tid & 63, wv = tid >> 6;
    const int r15 = lane & 15, gg = lane >> 4;
    const int b = blockIdx.x & 7, st = (blockIdx.x >> 3) & 31, dt = blockIdx.x >> 8;
    const int t0 = st * 128;

    f32x4 acc[2][8];
#pragma unroll
    for (int mt = 0; mt < 2; ++mt)
#pragma unroll
      for (int nt = 0; nt < 8; ++nt) acc[mt][nt] = (f32x4)0.f;

#pragma unroll
    for (int ks = 0; ks < 2; ++ks) {
        bf16x8 ah[2], al[2];
#pragma unroll
        for (int mt = 0; mt < 2; ++mt) {
            size_t ri = ((size_t)b*Ss + t0 + wv*32 + mt*16 + r15)*Kk + ks*32 + gg*8;
            ah[mt] = *(const bf16x8*)&rwh[ri];
            al[mt] = *(const bf16x8*)&rwl[ri];
        }
#pragma unroll
        for (int nt = 0; nt < 8; ++nt) {
            size_t bi = ((size_t)b*Dd + dt*128 + nt*16 + r15)*Kk + ks*32 + gg*8;
            bf16x8 bh = *(const bf16x8*)&aph[bi];
            bf16x8 bl = *(const bf16x8*)&apl[bi];
#pragma unroll
            for (int mt = 0; mt < 2; ++mt)
                acc[mt][nt] = mm3(ah[mt], al[mt], bh, bl, acc[mt][nt]);
        }
    }
#pragma unroll
    for (int nt = 0; nt < 8; ++nt) {
        float bp = b_p[dt*128 + nt*16 + r15];
#pragma unroll
        for (int mt = 0; mt < 2; ++mt)
#pragma unroll
          for (int j = 0; j < 4; ++j)
            out[((size_t)b*Ss + t0 + wv*32 + mt*16 + gg*4 + j)*Dd + dt*128 + nt*16 + r15]
                = acc[mt][nt][j] + bp;
    }
}

extern "C" void kernel_launch(void* const* d_in, const int* in_sizes, int n_in,
                              void* d_out, int out_size, void* d_ws, size_t ws_size,
                              hipStream_t stream)
{
    const float* x     = (const float*)d_in[0];
    const float* efas  = (const float*)d_in[1];
    const float* w_e   = (const float*)d_in[2];
    const float* b_e   = (const float*)d_in[3];
    const float* w1    = (const float*)d_in[4];
    const float* b1    = (const float*)d_in[5];
    const float* w2    = (const float*)d_in[6];
    const float* b2    = (const float*)d_in[7];
    const float* w_qkv = (const float*)d_in[8];
    const float* b_qkv = (const float*)d_in[9];
    const float* w_o   = (const float*)d_in[10];
    const float* b_o   = (const float*)d_in[11];
    const float* w_p   = (const float*)d_in[12];
    const float* b_p   = (const float*)d_in[13];
    float* out = (float*)d_out;
    char* ws = (char*)d_ws;

    ushort* w1h = (ushort*)(ws + OFF_W1H); ushort* w1l = (ushort*)(ws + OFF_W1L);
    ushort* w2h = (ushort*)(ws + OFF_W2H); ushort* w2l = (ushort*)(ws + OFF_W2L);
    ushort* wqh = (ushort*)(ws + OFF_WQH); ushort* wql = (ushort*)(ws + OFF_WQL);
    ushort* woh = (ushort*)(ws + OFF_WOH); ushort* wol = (ushort*)(ws + OFF_WOL);
    ushort* wph = (ushort*)(ws + OFF_WPH); ushort* wpl = (ushort*)(ws + OFF_WPL);
    ushort* rwh = (ushort*)(ws + OFF_RWH); ushort* rwl = (ushort*)(ws + OFF_RWL);
    float*  aif = (float*) (ws + OFF_AIF);
    ushort* aih = (ushort*)(ws + OFF_AIH); ushort* ail = (ushort*)(ws + OFF_AIL);
    ushort* rfh = (ushort*)(ws + OFF_RFH); ushort* rfl = (ushort*)(ws + OFF_RFL);
    ushort* qkh = (ushort*)(ws + OFF_QKH); ushort* qkl = (ushort*)(ws + OFF_QKL);
    ushort* vth = (ushort*)(ws + OFF_VTH); ushort* vtl = (ushort*)(ws + OFF_VTL);
    ushort* ath = (ushort*)(ws + OFF_ATH); ushort* atl = (ushort*)(ws + OFF_ATL);
    ushort* aoh = (ushort*)(ws + OFF_AOH); ushort* aol = (ushort*)(ws + OFF_AOL);
    ushort* aph = (ushort*)(ws + OFF_APH); ushort* apl = (ushort*)(ws + OFF_APL);

    hipLaunchKernelGGL(k_prep, dim3(1297), dim3(TB), 0, stream,
                       w1, w2, w_qkv, w_o, w_p,
                       w1h, w1l, w2h, w2l, wqh, wql, woh, wol, wph, wpl);
    hipLaunchKernelGGL(k_zero, dim3(512), dim3(TB), 0, stream,
                       aif, (int)(SZ_AIF / 16));
    hipLaunchKernelGGL(k_route, dim3(256), dim3(TB), 0, stream,
                       x, efas, w_e, b_e, b1, b2, w1h, w1l, w2h, w2l,
                       rwh, rwl, rfh, rfl);
    hipLaunchKernelGGL(k_anchor, dim3(1024), dim3(TB), 0, stream, x, rfh, rfl, aif);
    hipLaunchKernelGGL(k_cvt, dim3(512), dim3(TB), 0, stream, aif, aih, ail);
    hipLaunchKernelGGL((k_gemm<3072, 1>), dim3(384), dim3(TB), 0, stream,
                       aih, ail, wqh, wql, b_qkv, qkh, qkl, vth, vtl);
    hipLaunchKernelGGL(k_attn, dim3(64), dim3(TB), 0, stream,
                       qkh, qkl, vth, vtl, ath, atl);
    hipLaunchKernelGGL((k_gemm<1024, 0>), dim3(128), dim3(TB), 0, stream,
                       ath, atl, woh, wol, b_o, aoh, aol,
                       (ushort*)nullptr, (ushort*)nullptr);
    hipLaunchKernelGGL((k_gemm<1024, 2>), dim3(128), dim3(TB), 0, stream,
                       aoh, aol, wph, wpl, (const float*)nullptr,
                       (ushort*)nullptr, (ushort*)nullptr, aph, apl);
    hipLaunchKernelGGL(k_scatter, dim3(2048), dim3(TB), 0, stream,
                       rwh, rwl, aph, apl, b_p, out);
}